// Round 15
// baseline (103.375 us; speedup 1.0000x reference)
//
#include <hip/hip_runtime.h>

#define NV    500000
#define ND    64
#define NH    4
#define NHID  256
#define NS    10000
#define NOUT  128
#define GSAMP 2                 // samples per block
#define FUSED_GRID (NS / GSAMP) // 5000

typedef __attribute__((ext_vector_type(8))) _Float16 f16x8;
typedef __attribute__((ext_vector_type(4))) _Float16 f16x4;
typedef __attribute__((ext_vector_type(2))) __fp16   hf16x2;   // cvt_pkrtz result type
typedef __attribute__((ext_vector_type(4))) float    f32x4;

// ---------------------------------------------------------------------------
// Kernel W: write W_v as hi/lo f16 MFMA fragments in exact lane order.
// ---------------------------------------------------------------------------
__global__ __launch_bounds__(256) void wconv_kernel(
    const float* __restrict__ Wv, _Float16* __restrict__ WfH,
    _Float16* __restrict__ WfL)
{
    const int tid  = blockIdx.x * 256 + threadIdx.x;  // 0..2047
    const int lane = tid & 63;
    const int slot = tid >> 6;        // 0..31
    const int ks   = slot & 1;
    const int jt   = (slot >> 1) & 3;
    const int h    = slot >> 3;
    const int vcol = lane & 15;
    const int g    = lane >> 4;
    const int j    = h * 64 + jt * 16 + vcol;
    const int kb   = ks * 32 + g * 8;
    f16x8 hv, lv;
#pragma unroll
    for (int i = 0; i < 8; ++i) {
        const float w = Wv[(size_t)(kb + i) * NHID + j];
        const _Float16 hh = (_Float16)w;
        hv[i] = hh;
        lv[i] = (_Float16)(w - (float)hh);
    }
    *reinterpret_cast<f16x8*>(WfH + ((size_t)slot << 9) + (lane << 3)) = hv;
    *reinterpret_cast<f16x8*>(WfL + ((size_t)slot << 9) + (lane << 3)) = lv;
}

// ---------------------------------------------------------------------------
// Kernel B: segment boundaries from the SORTED map.
// ---------------------------------------------------------------------------
__global__ void bounds_kernel(const int* __restrict__ map, int* __restrict__ start)
{
    const int v = blockIdx.x * blockDim.x + threadIdx.x;
    if (v >= NV) return;
    const int cur = map[v];
    if (v == 0) {
        for (int s = 0; s <= cur; ++s) start[s] = 0;
    } else {
        const int prev = map[v - 1];
        for (int s = prev + 1; s <= cur; ++s) start[s] = v;
    }
    if (v == NV - 1) {
        for (int s = cur + 1; s <= NS; ++s) start[s] = NV;
    }
}

// ---------------------------------------------------------------------------
// Fused: scores (split-f16 MFMA, R12-verified) -> online softmax -> PV MFMA
// pooling with k-permuted operands (pi(v) = (v&15)*4 + (v>>4) on BOTH sides).
// R15 fix vs R13/R14: PV C-rows are the 4 HEADS -> rescale/normalize each row
// with ITS head's r/l (broadcast via rbuf/lbuf), not the wave's own.
// ---------------------------------------------------------------------------
__global__ __launch_bounds__(256, 4) void fused_kernel(
    const float* __restrict__ emb,
    const _Float16* __restrict__ WfH, const _Float16* __restrict__ WfL,
    const int* __restrict__ start, float* __restrict__ pooled)
{
    __shared__ _Float16 EH[64 * 64];    // emb hi, row-major swizzled (8 KB)
    __shared__ _Float16 EL[64 * 64];    // emb lo, row-major swizzled (8 KB)
    __shared__ _Float16 EHt[64 * 64];   // emb hi, d-major, v'-permuted (8 KB)
    __shared__ _Float16 ELDS[16][72];   // e-matrix, k-permuted, padded (2.25 KB)
    __shared__ float    rbuf[NH];       // per-head chunk rescale factors
    __shared__ float    lbuf[NH];       // per-head final denominators

    const int t    = threadIdx.x;
    const int lane = t & 63;
    const int h    = t >> 6;          // wave id == head (scores) == d-block (PV)
    const int vcol = lane & 15;
    const int g    = lane >> 4;

    // ---- W fragments for head h: coalesced 16B/lane loads ----
    f16x8 wh[4][2], wl[4][2];
#pragma unroll
    for (int jt = 0; jt < 4; ++jt)
#pragma unroll
        for (int ks = 0; ks < 2; ++ks) {
            const int slot = ((h * 4 + jt) * 2 + ks);
            const size_t off = ((size_t)slot << 9) + (lane << 3);
            wh[jt][ks] = *reinterpret_cast<const f16x8*>(WfH + off);
            wl[jt][ks] = *reinterpret_cast<const f16x8*>(WfL + off);
        }

    // zero ELDS once (rows 4..15 / pad cols stay zero)
    for (int i = t; i < (16 * 72 * 2) / 4; i += 256)
        reinterpret_cast<unsigned*>(ELDS)[i] = 0u;

    const int s0   = blockIdx.x * GSAMP;
    const int srow = t >> 4;          // 0..15 (stage row base within chunk)
    const int sk4  = (t & 15) << 2;   // d base: 0..60
    const int woff = (srow << 7) + ((sk4 << 1) ^ ((srow & 7) << 4)); // EH/EL byte

    // PV constants
    const int dpv  = (h << 4) + vcol;                            // PV column d
    const int pvb0 = dpv * 128 + (((g    ) ^ (dpv & 7)) << 4);   // eb0 byte
    const int pvb1 = dpv * 128 + (((g + 4) ^ (dpv & 7)) << 4);   // eb1 byte
    const int epos = ((lane & 15) << 2) + (lane >> 4);           // pi(lane)

    for (int si = 0; si < GSAMP; ++si) {
        const int s  = s0 + si;
        const int st = start[s];
        const int en = start[s + 1];
        if (st >= en) { pooled[(size_t)s * NHID + t] = 0.f; continue; }

        f32x4 acc = {0.f, 0.f, 0.f, 0.f};
        float m = -1e30f, l = 0.f;

        for (int c0 = st; c0 < en; c0 += 64) {
            const int C = min(64, en - c0);

            // ---- load 4 rows (named regs), convert, stage EH/EL/EHt ----
            const float4 z4 = make_float4(0.f, 0.f, 0.f, 0.f);
            float4 x0 = (srow      < C) ? *reinterpret_cast<const float4*>(emb + (size_t)(c0 + srow     ) * ND + sk4) : z4;
            float4 x1 = (srow + 16 < C) ? *reinterpret_cast<const float4*>(emb + (size_t)(c0 + srow + 16) * ND + sk4) : z4;
            float4 x2 = (srow + 32 < C) ? *reinterpret_cast<const float4*>(emb + (size_t)(c0 + srow + 32) * ND + sk4) : z4;
            float4 x3 = (srow + 48 < C) ? *reinterpret_cast<const float4*>(emb + (size_t)(c0 + srow + 48) * ND + sk4) : z4;

            f16x4 hv0, hv1, hv2, hv3;
#define CONV_ONE(X, HV, IT)                                                   \
            {                                                                 \
                const hf16x2 a01 = __builtin_amdgcn_cvt_pkrtz(X.x, X.y);      \
                const hf16x2 a23 = __builtin_amdgcn_cvt_pkrtz(X.z, X.w);      \
                const float r0 = X.x - (float)a01[0];                         \
                const float r1 = X.y - (float)a01[1];                         \
                const float r2 = X.z - (float)a23[0];                         \
                const float r3 = X.w - (float)a23[1];                         \
                const hf16x2 b01 = __builtin_amdgcn_cvt_pkrtz(r0, r1);        \
                const hf16x2 b23 = __builtin_amdgcn_cvt_pkrtz(r2, r3);        \
                f16x4 lv;                                                     \
                HV[0] = (_Float16)a01[0]; HV[1] = (_Float16)a01[1];           \
                HV[2] = (_Float16)a23[0]; HV[3] = (_Float16)a23[1];           \
                lv[0] = (_Float16)b01[0]; lv[1] = (_Float16)b01[1];           \
                lv[2] = (_Float16)b23[0]; lv[3] = (_Float16)b23[1];           \
                *reinterpret_cast<f16x4*>((char*)EH + woff + (IT << 11)) = HV;\
                *reinterpret_cast<f16x4*>((char*)EL + woff + (IT << 11)) = lv;\
            }
            CONV_ONE(x0, hv0, 0)
            CONV_ONE(x1, hv1, 1)
            CONV_ONE(x2, hv2, 2)
            CONV_ONE(x3, hv3, 3)
#undef CONV_ONE
            // EHt: per d (jj), the 4 it-values are consecutive v' = srow*4..+3
#pragma unroll
            for (int jj = 0; jj < 4; ++jj) {
                const int d = sk4 + jj;
                f16x4 w4;
                w4[0] = hv0[jj]; w4[1] = hv1[jj]; w4[2] = hv2[jj]; w4[3] = hv3[jj];
                const int ob = d * 128 + ((((srow >> 1)) ^ (d & 7)) << 4) + ((srow & 1) << 3);
                *reinterpret_cast<f16x4*>((char*)EHt + ob) = w4;
            }
            __syncthreads();   // bar1: stage visible

            // ---- scores for head h (R12-verified path) ----
            float sv[4];
            __builtin_amdgcn_s_setprio(1);
#pragma unroll
            for (int vt = 0; vt < 4; ++vt) {
                const int row = (vt << 4) + vcol;
                const int rb  = row << 7;
                const int sw  = (row & 7) << 4;
                const f16x8 bh0 = *reinterpret_cast<const f16x8*>(
                    (const char*)EH + rb + (((g << 4)) ^ sw));
                const f16x8 bh1 = *reinterpret_cast<const f16x8*>(
                    (const char*)EH + rb + ((64 | (g << 4)) ^ sw));
                const f16x8 bl0 = *reinterpret_cast<const f16x8*>(
                    (const char*)EL + rb + (((g << 4)) ^ sw));
                const f16x8 bl1 = *reinterpret_cast<const f16x8*>(
                    (const char*)EL + rb + ((64 | (g << 4)) ^ sw));
                float sreg = 0.f;
#pragma unroll
                for (int jt = 0; jt < 4; ++jt) {
                    f32x4 a4 = {0.f, 0.f, 0.f, 0.f};
                    a4 = __builtin_amdgcn_mfma_f32_16x16x32_f16(wh[jt][0], bh0, a4, 0, 0, 0);
                    a4 = __builtin_amdgcn_mfma_f32_16x16x32_f16(wh[jt][1], bh1, a4, 0, 0, 0);
                    a4 = __builtin_amdgcn_mfma_f32_16x16x32_f16(wh[jt][0], bl0, a4, 0, 0, 0);
                    a4 = __builtin_amdgcn_mfma_f32_16x16x32_f16(wh[jt][1], bl1, a4, 0, 0, 0);
                    a4 = __builtin_amdgcn_mfma_f32_16x16x32_f16(wl[jt][0], bh0, a4, 0, 0, 0);
                    a4 = __builtin_amdgcn_mfma_f32_16x16x32_f16(wl[jt][1], bh1, a4, 0, 0, 0);
                    sreg += a4[0]*a4[0] + a4[1]*a4[1] + a4[2]*a4[2] + a4[3]*a4[3];
                }
                sreg += __shfl_xor(sreg, 16, 64);
                sreg += __shfl_xor(sreg, 32, 64);
                sv[vt] = sreg;
            }
            __builtin_amdgcn_s_setprio(0);

            // lane's own score (v = lane): static cndmask select
            const float scA = (lane & 16) ? sv[1] : sv[0];
            const float scB = (lane & 16) ? sv[3] : sv[2];
            const float scO = (lane & 32) ? scB : scA;

            // ---- online softmax update (wave-local, head h) ----
            const float sc = (lane < C) ? scO : -1e30f;
            float cmax = sc;
#pragma unroll
            for (int off = 1; off < 64; off <<= 1)
                cmax = fmaxf(cmax, __shfl_xor(cmax, off, 64));
            const float mn = fmaxf(m, cmax);
            const float r  = __expf(m - mn);
            const float e  = (lane < C) ? __expf(sc - mn) : 0.f;
            float csum = e;
#pragma unroll
            for (int off = 1; off < 64; off <<= 1)
                csum += __shfl_xor(csum, off, 64);
            l = l * r + csum;
            m = mn;

            // publish e (f16, k-permuted) and this head's rescale factor
            ELDS[h][epos] = (_Float16)e;
            if (lane == 0) rbuf[h] = r;
            __syncthreads();   // bar2: e + EHt + rbuf visible

            // ---- PV: C[m=head][n=d] += e x emb; rescale row m by r_m ----
            const float rb0 = rbuf[0], rb1 = rbuf[1], rb2 = rbuf[2], rb3 = rbuf[3];
            const f16x8 ea0 = *reinterpret_cast<const f16x8*>(&ELDS[vcol][g << 3]);
            const f16x8 ea1 = *reinterpret_cast<const f16x8*>(&ELDS[vcol][(g << 3) + 32]);
            const f16x8 eb0 = *reinterpret_cast<const f16x8*>((const char*)EHt + pvb0);
            const f16x8 eb1 = *reinterpret_cast<const f16x8*>((const char*)EHt + pvb1);
            acc[0] *= rb0; acc[1] *= rb1; acc[2] *= rb2; acc[3] *= rb3;
            acc = __builtin_amdgcn_mfma_f32_16x16x32_f16(ea0, eb0, acc, 0, 0, 0);
            acc = __builtin_amdgcn_mfma_f32_16x16x32_f16(ea1, eb1, acc, 0, 0, 0);
            __syncthreads();   // bar3: PV reads done before next stage
        }

        // ---- publish per-head denominators, then write pooled ----
        if (lane == 0) lbuf[h] = l;
        __syncthreads();
        if (g == 0) {
#pragma unroll
            for (int rr = 0; rr < 4; ++rr)
                pooled[(size_t)s * NHID + rr * 64 + (h << 4) + vcol] =
                    acc[rr] / lbuf[rr];
        }
    }
}

// ---------------------------------------------------------------------------
// Kernel D: out = pooled @ W_out
// ---------------------------------------------------------------------------
__global__ __launch_bounds__(256) void out_kernel(
    const float* __restrict__ pooled, const float* __restrict__ Wout,
    float* __restrict__ out)
{
    __shared__ float Pt[16][260];
    const int t = threadIdx.x;
    const int sbase = blockIdx.x << 4;
#pragma unroll
    for (int it = 0; it < 4; ++it) {
        const int idx = t + (it << 8);
        const int row = idx >> 6;
        const int c4 = (idx & 63) << 2;
        *reinterpret_cast<float4*>(&Pt[row][c4]) =
            *reinterpret_cast<const float4*>(pooled + (size_t)(sbase + row) * NHID + c4);
    }
    __syncthreads();
    const int oc = (t & 31) << 2;
    const int sg = t >> 5;
    float a0x = 0.f, a0y = 0.f, a0z = 0.f, a0w = 0.f;
    float a1x = 0.f, a1y = 0.f, a1z = 0.f, a1w = 0.f;
#pragma unroll 4
    for (int k = 0; k < NHID; ++k) {
        const float4 w = *reinterpret_cast<const float4*>(Wout + (size_t)k * NOUT + oc);
        const float p0 = Pt[(sg << 1) + 0][k];
        const float p1 = Pt[(sg << 1) + 1][k];
        a0x = fmaf(p0, w.x, a0x); a0y = fmaf(p0, w.y, a0y);
        a0z = fmaf(p0, w.z, a0z); a0w = fmaf(p0, w.w, a0w);
        a1x = fmaf(p1, w.x, a1x); a1y = fmaf(p1, w.y, a1y);
        a1z = fmaf(p1, w.z, a1z); a1w = fmaf(p1, w.w, a1w);
    }
    *reinterpret_cast<float4*>(out + (size_t)(sbase + (sg << 1) + 0) * NOUT + oc) =
        make_float4(a0x, a0y, a0z, a0w);
    *reinterpret_cast<float4*>(out + (size_t)(sbase + (sg << 1) + 1) * NOUT + oc) =
        make_float4(a1x, a1y, a1z, a1w);
}

// ---------------------------------------------------------------------------
extern "C" void kernel_launch(void* const* d_in, const int* in_sizes, int n_in,
                              void* d_out, int out_size, void* d_ws, size_t ws_size,
                              hipStream_t stream)
{
    const float* emb  = (const float*)d_in[0];
    const float* Wv   = (const float*)d_in[1];
    const float* Wout = (const float*)d_in[2];
    const int*   map  = (const int*)d_in[3];
    float* out = (float*)d_out;

    char* ws = (char*)d_ws;
    float*    pooled = (float*)ws;                    // 10,240,000 B
    int*      start  = (int*)(ws + 10240000);         //     40,004 B
    _Float16* WfH    = (_Float16*)(ws + 10280064);    //     32,768 B
    _Float16* WfL    = (_Float16*)(ws + 10312832);    //     32,768 B

    wconv_kernel<<<8, 256, 0, stream>>>(Wv, WfH, WfL);
    bounds_kernel<<<(NV + 255) / 256, 256, 0, stream>>>(map, start);
    fused_kernel<<<FUSED_GRID, 256, 0, stream>>>(emb, WfH, WfL, start, pooled);
    out_kernel<<<NS / 16, 256, 0, stream>>>(pooled, Wout, out);
}

// Round 16
// 102.863 us; speedup vs baseline: 1.0050x; 1.0050x over previous
//
#include <hip/hip_runtime.h>

#define NV    500000
#define ND    64
#define NH    4
#define NHID  256
#define NS    10000
#define NOUT  128
#define GSAMP 4                 // samples per block
#define FUSED_GRID (NS / GSAMP) // 2500

typedef __attribute__((ext_vector_type(8))) _Float16 f16x8;
typedef __attribute__((ext_vector_type(4))) _Float16 f16x4;
typedef __attribute__((ext_vector_type(2))) __fp16   hf16x2;   // cvt_pkrtz result type
typedef __attribute__((ext_vector_type(4))) float    f32x4;

// ---------------------------------------------------------------------------
// Kernel W: write W_v as hi/lo f16 MFMA fragments in exact lane order.
// ---------------------------------------------------------------------------
__global__ __launch_bounds__(256) void wconv_kernel(
    const float* __restrict__ Wv, _Float16* __restrict__ WfH,
    _Float16* __restrict__ WfL)
{
    const int tid  = blockIdx.x * 256 + threadIdx.x;  // 0..2047
    const int lane = tid & 63;
    const int slot = tid >> 6;        // 0..31
    const int ks   = slot & 1;
    const int jt   = (slot >> 1) & 3;
    const int h    = slot >> 3;
    const int vcol = lane & 15;
    const int g    = lane >> 4;
    const int j    = h * 64 + jt * 16 + vcol;
    const int kb   = ks * 32 + g * 8;
    f16x8 hv, lv;
#pragma unroll
    for (int i = 0; i < 8; ++i) {
        const float w = Wv[(size_t)(kb + i) * NHID + j];
        const _Float16 hh = (_Float16)w;
        hv[i] = hh;
        lv[i] = (_Float16)(w - (float)hh);
    }
    *reinterpret_cast<f16x8*>(WfH + ((size_t)slot << 9) + (lane << 3)) = hv;
    *reinterpret_cast<f16x8*>(WfL + ((size_t)slot << 9) + (lane << 3)) = lv;
}

// ---------------------------------------------------------------------------
// Kernel B: segment boundaries from the SORTED map.
// ---------------------------------------------------------------------------
__global__ void bounds_kernel(const int* __restrict__ map, int* __restrict__ start)
{
    const int v = blockIdx.x * blockDim.x + threadIdx.x;
    if (v >= NV) return;
    const int cur = map[v];
    if (v == 0) {
        for (int s = 0; s <= cur; ++s) start[s] = 0;
    } else {
        const int prev = map[v - 1];
        for (int s = prev + 1; s <= cur; ++s) start[s] = v;
    }
    if (v == NV - 1) {
        for (int s = cur + 1; s <= NS; ++s) start[s] = NV;
    }
}

// ---------------------------------------------------------------------------
// Fused: scores (split-f16 MFMA, verified) -> online softmax -> PV MFMA
// pooling with k-permuted operands (pi(v) = (v&15)*4 + (v>>4) on BOTH sides).
// R16 vs R15: (a) EHt row stride 128->136 B (rotation spreads banks; no XOR;
// writes d*136+srow*8; PV reads = 2x b64 at d*136+g*16 / +64) — fixes the
// measured 4.9M bank conflicts; (b) GSAMP=4 — halves W-frag L2 traffic and
// amortizes the per-block W prologue.
// ---------------------------------------------------------------------------
__global__ __launch_bounds__(256, 4) void fused_kernel(
    const float* __restrict__ emb,
    const _Float16* __restrict__ WfH, const _Float16* __restrict__ WfL,
    const int* __restrict__ start, float* __restrict__ pooled)
{
    __shared__ _Float16 EH[64 * 64];    // emb hi, row-major swizzled (8 KB)
    __shared__ _Float16 EL[64 * 64];    // emb lo, row-major swizzled (8 KB)
    __shared__ _Float16 EHt[64 * 68];   // emb hi, d-major, v'-permuted, 136B rows (8.5 KB)
    __shared__ _Float16 ELDS[16][72];   // e-matrix, k-permuted, padded (2.25 KB)
    __shared__ float    rbuf[NH];       // per-head chunk rescale factors
    __shared__ float    lbuf[NH];       // per-head final denominators

    const int t    = threadIdx.x;
    const int lane = t & 63;
    const int h    = t >> 6;          // wave id == head (scores) == d-block (PV)
    const int vcol = lane & 15;
    const int g    = lane >> 4;

    // ---- W fragments for head h: coalesced 16B/lane loads ----
    f16x8 wh[4][2], wl[4][2];
#pragma unroll
    for (int jt = 0; jt < 4; ++jt)
#pragma unroll
        for (int ks = 0; ks < 2; ++ks) {
            const int slot = ((h * 4 + jt) * 2 + ks);
            const size_t off = ((size_t)slot << 9) + (lane << 3);
            wh[jt][ks] = *reinterpret_cast<const f16x8*>(WfH + off);
            wl[jt][ks] = *reinterpret_cast<const f16x8*>(WfL + off);
        }

    // zero ELDS once (rows 4..15 / pad cols stay zero)
    for (int i = t; i < (16 * 72 * 2) / 4; i += 256)
        reinterpret_cast<unsigned*>(ELDS)[i] = 0u;

    const int s0   = blockIdx.x * GSAMP;
    const int srow = t >> 4;          // 0..15 (stage row base within chunk)
    const int sk4  = (t & 15) << 2;   // d base: 0..60
    const int woff = (srow << 7) + ((sk4 << 1) ^ ((srow & 7) << 4)); // EH/EL byte

    // PV constants
    const int dpv  = (h << 4) + vcol;            // PV column d
    const int pvb  = dpv * 136 + (g << 4);       // eb0 byte base (b64-aligned)
    const int epos = ((lane & 15) << 2) + (lane >> 4);   // pi(lane)

    for (int si = 0; si < GSAMP; ++si) {
        const int s  = s0 + si;
        const int st = start[s];
        const int en = start[s + 1];
        if (st >= en) { pooled[(size_t)s * NHID + t] = 0.f; continue; }

        f32x4 acc = {0.f, 0.f, 0.f, 0.f};
        float m = -1e30f, l = 0.f;

        for (int c0 = st; c0 < en; c0 += 64) {
            const int C = min(64, en - c0);

            // ---- load 4 rows (named regs), convert, stage EH/EL/EHt ----
            const float4 z4 = make_float4(0.f, 0.f, 0.f, 0.f);
            float4 x0 = (srow      < C) ? *reinterpret_cast<const float4*>(emb + (size_t)(c0 + srow     ) * ND + sk4) : z4;
            float4 x1 = (srow + 16 < C) ? *reinterpret_cast<const float4*>(emb + (size_t)(c0 + srow + 16) * ND + sk4) : z4;
            float4 x2 = (srow + 32 < C) ? *reinterpret_cast<const float4*>(emb + (size_t)(c0 + srow + 32) * ND + sk4) : z4;
            float4 x3 = (srow + 48 < C) ? *reinterpret_cast<const float4*>(emb + (size_t)(c0 + srow + 48) * ND + sk4) : z4;

            f16x4 hv0, hv1, hv2, hv3;
#define CONV_ONE(X, HV, IT)                                                   \
            {                                                                 \
                const hf16x2 a01 = __builtin_amdgcn_cvt_pkrtz(X.x, X.y);      \
                const hf16x2 a23 = __builtin_amdgcn_cvt_pkrtz(X.z, X.w);      \
                const float r0 = X.x - (float)a01[0];                         \
                const float r1 = X.y - (float)a01[1];                         \
                const float r2 = X.z - (float)a23[0];                         \
                const float r3 = X.w - (float)a23[1];                         \
                const hf16x2 b01 = __builtin_amdgcn_cvt_pkrtz(r0, r1);        \
                const hf16x2 b23 = __builtin_amdgcn_cvt_pkrtz(r2, r3);        \
                f16x4 lv;                                                     \
                HV[0] = (_Float16)a01[0]; HV[1] = (_Float16)a01[1];           \
                HV[2] = (_Float16)a23[0]; HV[3] = (_Float16)a23[1];           \
                lv[0] = (_Float16)b01[0]; lv[1] = (_Float16)b01[1];           \
                lv[2] = (_Float16)b23[0]; lv[3] = (_Float16)b23[1];           \
                *reinterpret_cast<f16x4*>((char*)EH + woff + (IT << 11)) = HV;\
                *reinterpret_cast<f16x4*>((char*)EL + woff + (IT << 11)) = lv;\
            }
            CONV_ONE(x0, hv0, 0)
            CONV_ONE(x1, hv1, 1)
            CONV_ONE(x2, hv2, 2)
            CONV_ONE(x3, hv3, 3)
#undef CONV_ONE
            // EHt: per d (jj), the 4 it-values are consecutive v' = srow*4..+3
#pragma unroll
            for (int jj = 0; jj < 4; ++jj) {
                const int d = sk4 + jj;
                f16x4 w4;
                w4[0] = hv0[jj]; w4[1] = hv1[jj]; w4[2] = hv2[jj]; w4[3] = hv3[jj];
                const int ob = d * 136 + (srow << 3);     // b64-aligned, bank-rotated
                *reinterpret_cast<f16x4*>((char*)EHt + ob) = w4;
            }
            __syncthreads();   // bar1: stage visible

            // ---- scores for head h (verified path) ----
            float sv[4];
            __builtin_amdgcn_s_setprio(1);
#pragma unroll
            for (int vt = 0; vt < 4; ++vt) {
                const int row = (vt << 4) + vcol;
                const int rb  = row << 7;
                const int sw  = (row & 7) << 4;
                const f16x8 bh0 = *reinterpret_cast<const f16x8*>(
                    (const char*)EH + rb + (((g << 4)) ^ sw));
                const f16x8 bh1 = *reinterpret_cast<const f16x8*>(
                    (const char*)EH + rb + ((64 | (g << 4)) ^ sw));
                const f16x8 bl0 = *reinterpret_cast<const f16x8*>(
                    (const char*)EL + rb + (((g << 4)) ^ sw));
                const f16x8 bl1 = *reinterpret_cast<const f16x8*>(
                    (const char*)EL + rb + ((64 | (g << 4)) ^ sw));
                float sreg = 0.f;
#pragma unroll
                for (int jt = 0; jt < 4; ++jt) {
                    f32x4 a4 = {0.f, 0.f, 0.f, 0.f};
                    a4 = __builtin_amdgcn_mfma_f32_16x16x32_f16(wh[jt][0], bh0, a4, 0, 0, 0);
                    a4 = __builtin_amdgcn_mfma_f32_16x16x32_f16(wh[jt][1], bh1, a4, 0, 0, 0);
                    a4 = __builtin_amdgcn_mfma_f32_16x16x32_f16(wh[jt][0], bl0, a4, 0, 0, 0);
                    a4 = __builtin_amdgcn_mfma_f32_16x16x32_f16(wh[jt][1], bl1, a4, 0, 0, 0);
                    a4 = __builtin_amdgcn_mfma_f32_16x16x32_f16(wl[jt][0], bh0, a4, 0, 0, 0);
                    a4 = __builtin_amdgcn_mfma_f32_16x16x32_f16(wl[jt][1], bh1, a4, 0, 0, 0);
                    sreg += a4[0]*a4[0] + a4[1]*a4[1] + a4[2]*a4[2] + a4[3]*a4[3];
                }
                sreg += __shfl_xor(sreg, 16, 64);
                sreg += __shfl_xor(sreg, 32, 64);
                sv[vt] = sreg;
            }
            __builtin_amdgcn_s_setprio(0);

            // lane's own score (v = lane): static cndmask select
            const float scA = (lane & 16) ? sv[1] : sv[0];
            const float scB = (lane & 16) ? sv[3] : sv[2];
            const float scO = (lane & 32) ? scB : scA;

            // ---- online softmax update (wave-local, head h) ----
            const float sc = (lane < C) ? scO : -1e30f;
            float cmax = sc;
#pragma unroll
            for (int off = 1; off < 64; off <<= 1)
                cmax = fmaxf(cmax, __shfl_xor(cmax, off, 64));
            const float mn = fmaxf(m, cmax);
            const float r  = __expf(m - mn);
            const float e  = (lane < C) ? __expf(sc - mn) : 0.f;
            float csum = e;
#pragma unroll
            for (int off = 1; off < 64; off <<= 1)
                csum += __shfl_xor(csum, off, 64);
            l = l * r + csum;
            m = mn;

            // publish e (f16, k-permuted) and this head's rescale factor
            ELDS[h][epos] = (_Float16)e;
            if (lane == 0) rbuf[h] = r;
            __syncthreads();   // bar2: e + EHt + rbuf visible

            // ---- PV: C[m=head][n=d] += e x emb; rescale row m by r_m ----
            const float rb0 = rbuf[0], rb1 = rbuf[1], rb2 = rbuf[2], rb3 = rbuf[3];
            const f16x8 ea0 = *reinterpret_cast<const f16x8*>(&ELDS[vcol][g << 3]);
            const f16x8 ea1 = *reinterpret_cast<const f16x8*>(&ELDS[vcol][(g << 3) + 32]);
            const f16x4 b0lo = *reinterpret_cast<const f16x4*>((const char*)EHt + pvb);
            const f16x4 b0hi = *reinterpret_cast<const f16x4*>((const char*)EHt + pvb + 8);
            const f16x4 b1lo = *reinterpret_cast<const f16x4*>((const char*)EHt + pvb + 64);
            const f16x4 b1hi = *reinterpret_cast<const f16x4*>((const char*)EHt + pvb + 72);
            f16x8 eb0, eb1;
            eb0[0]=b0lo[0]; eb0[1]=b0lo[1]; eb0[2]=b0lo[2]; eb0[3]=b0lo[3];
            eb0[4]=b0hi[0]; eb0[5]=b0hi[1]; eb0[6]=b0hi[2]; eb0[7]=b0hi[3];
            eb1[0]=b1lo[0]; eb1[1]=b1lo[1]; eb1[2]=b1lo[2]; eb1[3]=b1lo[3];
            eb1[4]=b1hi[0]; eb1[5]=b1hi[1]; eb1[6]=b1hi[2]; eb1[7]=b1hi[3];
            acc[0] *= rb0; acc[1] *= rb1; acc[2] *= rb2; acc[3] *= rb3;
            acc = __builtin_amdgcn_mfma_f32_16x16x32_f16(ea0, eb0, acc, 0, 0, 0);
            acc = __builtin_amdgcn_mfma_f32_16x16x32_f16(ea1, eb1, acc, 0, 0, 0);
            __syncthreads();   // bar3: PV reads done before next stage
        }

        // ---- publish per-head denominators, then write pooled ----
        if (lane == 0) lbuf[h] = l;
        __syncthreads();
        if (g == 0) {
#pragma unroll
            for (int rr = 0; rr < 4; ++rr)
                pooled[(size_t)s * NHID + rr * 64 + (h << 4) + vcol] =
                    acc[rr] / lbuf[rr];
        }
    }
}

// ---------------------------------------------------------------------------
// Kernel D: out = pooled @ W_out
// ---------------------------------------------------------------------------
__global__ __launch_bounds__(256) void out_kernel(
    const float* __restrict__ pooled, const float* __restrict__ Wout,
    float* __restrict__ out)
{
    __shared__ float Pt[16][260];
    const int t = threadIdx.x;
    const int sbase = blockIdx.x << 4;
#pragma unroll
    for (int it = 0; it < 4; ++it) {
        const int idx = t + (it << 8);
        const int row = idx >> 6;
        const int c4 = (idx & 63) << 2;
        *reinterpret_cast<float4*>(&Pt[row][c4]) =
            *reinterpret_cast<const float4*>(pooled + (size_t)(sbase + row) * NHID + c4);
    }
    __syncthreads();
    const int oc = (t & 31) << 2;
    const int sg = t >> 5;
    float a0x = 0.f, a0y = 0.f, a0z = 0.f, a0w = 0.f;
    float a1x = 0.f, a1y = 0.f, a1z = 0.f, a1w = 0.f;
#pragma unroll 4
    for (int k = 0; k < NHID; ++k) {
        const float4 w = *reinterpret_cast<const float4*>(Wout + (size_t)k * NOUT + oc);
        const float p0 = Pt[(sg << 1) + 0][k];
        const float p1 = Pt[(sg << 1) + 1][k];
        a0x = fmaf(p0, w.x, a0x); a0y = fmaf(p0, w.y, a0y);
        a0z = fmaf(p0, w.z, a0z); a0w = fmaf(p0, w.w, a0w);
        a1x = fmaf(p1, w.x, a1x); a1y = fmaf(p1, w.y, a1y);
        a1z = fmaf(p1, w.z, a1z); a1w = fmaf(p1, w.w, a1w);
    }
    *reinterpret_cast<float4*>(out + (size_t)(sbase + (sg << 1) + 0) * NOUT + oc) =
        make_float4(a0x, a0y, a0z, a0w);
    *reinterpret_cast<float4*>(out + (size_t)(sbase + (sg << 1) + 1) * NOUT + oc) =
        make_float4(a1x, a1y, a1z, a1w);
}

// ---------------------------------------------------------------------------
extern "C" void kernel_launch(void* const* d_in, const int* in_sizes, int n_in,
                              void* d_out, int out_size, void* d_ws, size_t ws_size,
                              hipStream_t stream)
{
    const float* emb  = (const float*)d_in[0];
    const float* Wv   = (const float*)d_in[1];
    const float* Wout = (const float*)d_in[2];
    const int*   map  = (const int*)d_in[3];
    float* out = (float*)d_out;

    char* ws = (char*)d_ws;
    float*    pooled = (float*)ws;                    // 10,240,000 B
    int*      start  = (int*)(ws + 10240000);         //     40,004 B
    _Float16* WfH    = (_Float16*)(ws + 10280064);    //     32,768 B
    _Float16* WfL    = (_Float16*)(ws + 10312832);    //     32,768 B

    wconv_kernel<<<8, 256, 0, stream>>>(Wv, WfH, WfL);
    bounds_kernel<<<(NV + 255) / 256, 256, 0, stream>>>(map, start);
    fused_kernel<<<FUSED_GRID, 256, 0, stream>>>(emb, WfH, WfL, start, pooled);
    out_kernel<<<NS / 16, 256, 0, stream>>>(pooled, Wout, out);
}

// Round 17
// 101.368 us; speedup vs baseline: 1.0198x; 1.0147x over previous
//
#include <hip/hip_runtime.h>

#define NV    500000
#define ND    64
#define NH    4
#define NHID  256
#define NS    10000
#define NOUT  128
#define GSAMP 4                 // samples per block
#define FUSED_GRID (NS / GSAMP) // 2500

typedef __attribute__((ext_vector_type(8))) _Float16 f16x8;
typedef __attribute__((ext_vector_type(4))) _Float16 f16x4;
typedef __attribute__((ext_vector_type(2))) __fp16   hf16x2;   // cvt_pkrtz result type
typedef __attribute__((ext_vector_type(4))) float    f32x4;

// ---------------------------------------------------------------------------
// Kernel W: write W_v as hi/lo f16 MFMA fragments in exact lane order.
// ---------------------------------------------------------------------------
__global__ __launch_bounds__(256) void wconv_kernel(
    const float* __restrict__ Wv, _Float16* __restrict__ WfH,
    _Float16* __restrict__ WfL)
{
    const int tid  = blockIdx.x * 256 + threadIdx.x;  // 0..2047
    const int lane = tid & 63;
    const int slot = tid >> 6;        // 0..31
    const int ks   = slot & 1;
    const int jt   = (slot >> 1) & 3;
    const int h    = slot >> 3;
    const int vcol = lane & 15;
    const int g    = lane >> 4;
    const int j    = h * 64 + jt * 16 + vcol;
    const int kb   = ks * 32 + g * 8;
    f16x8 hv, lv;
#pragma unroll
    for (int i = 0; i < 8; ++i) {
        const float w = Wv[(size_t)(kb + i) * NHID + j];
        const _Float16 hh = (_Float16)w;
        hv[i] = hh;
        lv[i] = (_Float16)(w - (float)hh);
    }
    *reinterpret_cast<f16x8*>(WfH + ((size_t)slot << 9) + (lane << 3)) = hv;
    *reinterpret_cast<f16x8*>(WfL + ((size_t)slot << 9) + (lane << 3)) = lv;
}

// ---------------------------------------------------------------------------
// Kernel B: segment boundaries from the SORTED map.
// ---------------------------------------------------------------------------
__global__ void bounds_kernel(const int* __restrict__ map, int* __restrict__ start)
{
    const int v = blockIdx.x * blockDim.x + threadIdx.x;
    if (v >= NV) return;
    const int cur = map[v];
    if (v == 0) {
        for (int s = 0; s <= cur; ++s) start[s] = 0;
    } else {
        const int prev = map[v - 1];
        for (int s = prev + 1; s <= cur; ++s) start[s] = v;
    }
    if (v == NV - 1) {
        for (int s = cur + 1; s <= NS; ++s) start[s] = NV;
    }
}

// ---------------------------------------------------------------------------
// Fused: scores (split-f16 MFMA, verified) -> online softmax -> PV MFMA
// pooling with k-permuted operands (pi(v) = (v&15)*4 + (v>>4) on BOTH sides).
// R17 vs R16: scores v-tile loop guarded by wave-uniform (vt*16 < C) —
// skips the ~20% of score MFMAs that compute masked columns (avg C ~46).
// sv stays statically indexed (rule #20); branch is SGPR-uniform.
// ---------------------------------------------------------------------------
__global__ __launch_bounds__(256, 4) void fused_kernel(
    const float* __restrict__ emb,
    const _Float16* __restrict__ WfH, const _Float16* __restrict__ WfL,
    const int* __restrict__ start, float* __restrict__ pooled)
{
    __shared__ _Float16 EH[64 * 64];    // emb hi, row-major swizzled (8 KB)
    __shared__ _Float16 EL[64 * 64];    // emb lo, row-major swizzled (8 KB)
    __shared__ _Float16 EHt[64 * 68];   // emb hi, d-major, v'-permuted, 136B rows (8.5 KB)
    __shared__ _Float16 ELDS[16][72];   // e-matrix, k-permuted, padded (2.25 KB)
    __shared__ float    rbuf[NH];       // per-head chunk rescale factors
    __shared__ float    lbuf[NH];       // per-head final denominators

    const int t    = threadIdx.x;
    const int lane = t & 63;
    const int h    = t >> 6;          // wave id == head (scores) == d-block (PV)
    const int vcol = lane & 15;
    const int g    = lane >> 4;

    // ---- W fragments for head h: coalesced 16B/lane loads ----
    f16x8 wh[4][2], wl[4][2];
#pragma unroll
    for (int jt = 0; jt < 4; ++jt)
#pragma unroll
        for (int ks = 0; ks < 2; ++ks) {
            const int slot = ((h * 4 + jt) * 2 + ks);
            const size_t off = ((size_t)slot << 9) + (lane << 3);
            wh[jt][ks] = *reinterpret_cast<const f16x8*>(WfH + off);
            wl[jt][ks] = *reinterpret_cast<const f16x8*>(WfL + off);
        }

    // zero ELDS once (rows 4..15 / pad cols stay zero)
    for (int i = t; i < (16 * 72 * 2) / 4; i += 256)
        reinterpret_cast<unsigned*>(ELDS)[i] = 0u;

    const int s0   = blockIdx.x * GSAMP;
    const int srow = t >> 4;          // 0..15 (stage row base within chunk)
    const int sk4  = (t & 15) << 2;   // d base: 0..60
    const int woff = (srow << 7) + ((sk4 << 1) ^ ((srow & 7) << 4)); // EH/EL byte

    // PV constants
    const int dpv  = (h << 4) + vcol;            // PV column d
    const int pvb  = dpv * 136 + (g << 4);       // eb0 byte base (b64-aligned)
    const int epos = ((lane & 15) << 2) + (lane >> 4);   // pi(lane)

    for (int si = 0; si < GSAMP; ++si) {
        const int s  = s0 + si;
        const int st = start[s];
        const int en = start[s + 1];
        if (st >= en) { pooled[(size_t)s * NHID + t] = 0.f; continue; }

        f32x4 acc = {0.f, 0.f, 0.f, 0.f};
        float m = -1e30f, l = 0.f;

        for (int c0 = st; c0 < en; c0 += 64) {
            const int C = min(64, en - c0);

            // ---- load 4 rows (named regs), convert, stage EH/EL/EHt ----
            const float4 z4 = make_float4(0.f, 0.f, 0.f, 0.f);
            float4 x0 = (srow      < C) ? *reinterpret_cast<const float4*>(emb + (size_t)(c0 + srow     ) * ND + sk4) : z4;
            float4 x1 = (srow + 16 < C) ? *reinterpret_cast<const float4*>(emb + (size_t)(c0 + srow + 16) * ND + sk4) : z4;
            float4 x2 = (srow + 32 < C) ? *reinterpret_cast<const float4*>(emb + (size_t)(c0 + srow + 32) * ND + sk4) : z4;
            float4 x3 = (srow + 48 < C) ? *reinterpret_cast<const float4*>(emb + (size_t)(c0 + srow + 48) * ND + sk4) : z4;

            f16x4 hv0, hv1, hv2, hv3;
#define CONV_ONE(X, HV, IT)                                                   \
            {                                                                 \
                const hf16x2 a01 = __builtin_amdgcn_cvt_pkrtz(X.x, X.y);      \
                const hf16x2 a23 = __builtin_amdgcn_cvt_pkrtz(X.z, X.w);      \
                const float r0 = X.x - (float)a01[0];                         \
                const float r1 = X.y - (float)a01[1];                         \
                const float r2 = X.z - (float)a23[0];                         \
                const float r3 = X.w - (float)a23[1];                         \
                const hf16x2 b01 = __builtin_amdgcn_cvt_pkrtz(r0, r1);        \
                const hf16x2 b23 = __builtin_amdgcn_cvt_pkrtz(r2, r3);        \
                f16x4 lv;                                                     \
                HV[0] = (_Float16)a01[0]; HV[1] = (_Float16)a01[1];           \
                HV[2] = (_Float16)a23[0]; HV[3] = (_Float16)a23[1];           \
                lv[0] = (_Float16)b01[0]; lv[1] = (_Float16)b01[1];           \
                lv[2] = (_Float16)b23[0]; lv[3] = (_Float16)b23[1];           \
                *reinterpret_cast<f16x4*>((char*)EH + woff + (IT << 11)) = HV;\
                *reinterpret_cast<f16x4*>((char*)EL + woff + (IT << 11)) = lv;\
            }
            CONV_ONE(x0, hv0, 0)
            CONV_ONE(x1, hv1, 1)
            CONV_ONE(x2, hv2, 2)
            CONV_ONE(x3, hv3, 3)
#undef CONV_ONE
            // EHt: per d (jj), the 4 it-values are consecutive v' = srow*4..+3
#pragma unroll
            for (int jj = 0; jj < 4; ++jj) {
                const int d = sk4 + jj;
                f16x4 w4;
                w4[0] = hv0[jj]; w4[1] = hv1[jj]; w4[2] = hv2[jj]; w4[3] = hv3[jj];
                const int ob = d * 136 + (srow << 3);     // b64-aligned, bank-rotated
                *reinterpret_cast<f16x4*>((char*)EHt + ob) = w4;
            }
            __syncthreads();   // bar1: stage visible

            // ---- scores for head h; only occupied v-tiles (uniform guard) ---
            float sv[4];
            __builtin_amdgcn_s_setprio(1);
#pragma unroll
            for (int vt = 0; vt < 4; ++vt) {
                float sreg = 0.f;
                if ((vt << 4) < C) {   // wave-uniform (C from SGPRs)
                    const int row = (vt << 4) + vcol;
                    const int rb  = row << 7;
                    const int sw  = (row & 7) << 4;
                    const f16x8 bh0 = *reinterpret_cast<const f16x8*>(
                        (const char*)EH + rb + (((g << 4)) ^ sw));
                    const f16x8 bh1 = *reinterpret_cast<const f16x8*>(
                        (const char*)EH + rb + ((64 | (g << 4)) ^ sw));
                    const f16x8 bl0 = *reinterpret_cast<const f16x8*>(
                        (const char*)EL + rb + (((g << 4)) ^ sw));
                    const f16x8 bl1 = *reinterpret_cast<const f16x8*>(
                        (const char*)EL + rb + ((64 | (g << 4)) ^ sw));
#pragma unroll
                    for (int jt = 0; jt < 4; ++jt) {
                        f32x4 a4 = {0.f, 0.f, 0.f, 0.f};
                        a4 = __builtin_amdgcn_mfma_f32_16x16x32_f16(wh[jt][0], bh0, a4, 0, 0, 0);
                        a4 = __builtin_amdgcn_mfma_f32_16x16x32_f16(wh[jt][1], bh1, a4, 0, 0, 0);
                        a4 = __builtin_amdgcn_mfma_f32_16x16x32_f16(wh[jt][0], bl0, a4, 0, 0, 0);
                        a4 = __builtin_amdgcn_mfma_f32_16x16x32_f16(wh[jt][1], bl1, a4, 0, 0, 0);
                        a4 = __builtin_amdgcn_mfma_f32_16x16x32_f16(wl[jt][0], bh0, a4, 0, 0, 0);
                        a4 = __builtin_amdgcn_mfma_f32_16x16x32_f16(wl[jt][1], bh1, a4, 0, 0, 0);
                        sreg += a4[0]*a4[0] + a4[1]*a4[1] + a4[2]*a4[2] + a4[3]*a4[3];
                    }
                    sreg += __shfl_xor(sreg, 16, 64);
                    sreg += __shfl_xor(sreg, 32, 64);
                }
                sv[vt] = sreg;
            }
            __builtin_amdgcn_s_setprio(0);

            // lane's own score (v = lane): static cndmask select
            const float scA = (lane & 16) ? sv[1] : sv[0];
            const float scB = (lane & 16) ? sv[3] : sv[2];
            const float scO = (lane & 32) ? scB : scA;

            // ---- online softmax update (wave-local, head h) ----
            const float sc = (lane < C) ? scO : -1e30f;
            float cmax = sc;
#pragma unroll
            for (int off = 1; off < 64; off <<= 1)
                cmax = fmaxf(cmax, __shfl_xor(cmax, off, 64));
            const float mn = fmaxf(m, cmax);
            const float r  = __expf(m - mn);
            const float e  = (lane < C) ? __expf(sc - mn) : 0.f;
            float csum = e;
#pragma unroll
            for (int off = 1; off < 64; off <<= 1)
                csum += __shfl_xor(csum, off, 64);
            l = l * r + csum;
            m = mn;

            // publish e (f16, k-permuted) and this head's rescale factor
            ELDS[h][epos] = (_Float16)e;
            if (lane == 0) rbuf[h] = r;
            __syncthreads();   // bar2: e + EHt + rbuf visible

            // ---- PV: C[m=head][n=d] += e x emb; rescale row m by r_m ----
            const float rb0 = rbuf[0], rb1 = rbuf[1], rb2 = rbuf[2], rb3 = rbuf[3];
            const f16x8 ea0 = *reinterpret_cast<const f16x8*>(&ELDS[vcol][g << 3]);
            const f16x8 ea1 = *reinterpret_cast<const f16x8*>(&ELDS[vcol][(g << 3) + 32]);
            const f16x4 b0lo = *reinterpret_cast<const f16x4*>((const char*)EHt + pvb);
            const f16x4 b0hi = *reinterpret_cast<const f16x4*>((const char*)EHt + pvb + 8);
            const f16x4 b1lo = *reinterpret_cast<const f16x4*>((const char*)EHt + pvb + 64);
            const f16x4 b1hi = *reinterpret_cast<const f16x4*>((const char*)EHt + pvb + 72);
            f16x8 eb0, eb1;
            eb0[0]=b0lo[0]; eb0[1]=b0lo[1]; eb0[2]=b0lo[2]; eb0[3]=b0lo[3];
            eb0[4]=b0hi[0]; eb0[5]=b0hi[1]; eb0[6]=b0hi[2]; eb0[7]=b0hi[3];
            eb1[0]=b1lo[0]; eb1[1]=b1lo[1]; eb1[2]=b1lo[2]; eb1[3]=b1lo[3];
            eb1[4]=b1hi[0]; eb1[5]=b1hi[1]; eb1[6]=b1hi[2]; eb1[7]=b1hi[3];
            acc[0] *= rb0; acc[1] *= rb1; acc[2] *= rb2; acc[3] *= rb3;
            acc = __builtin_amdgcn_mfma_f32_16x16x32_f16(ea0, eb0, acc, 0, 0, 0);
            acc = __builtin_amdgcn_mfma_f32_16x16x32_f16(ea1, eb1, acc, 0, 0, 0);
            __syncthreads();   // bar3: PV reads done before next stage
        }

        // ---- publish per-head denominators, then write pooled ----
        if (lane == 0) lbuf[h] = l;
        __syncthreads();
        if (g == 0) {
#pragma unroll
            for (int rr = 0; rr < 4; ++rr)
                pooled[(size_t)s * NHID + rr * 64 + (h << 4) + vcol] =
                    acc[rr] / lbuf[rr];
        }
    }
}

// ---------------------------------------------------------------------------
// Kernel D: out = pooled @ W_out
// ---------------------------------------------------------------------------
__global__ __launch_bounds__(256) void out_kernel(
    const float* __restrict__ pooled, const float* __restrict__ Wout,
    float* __restrict__ out)
{
    __shared__ float Pt[16][260];
    const int t = threadIdx.x;
    const int sbase = blockIdx.x << 4;
#pragma unroll
    for (int it = 0; it < 4; ++it) {
        const int idx = t + (it << 8);
        const int row = idx >> 6;
        const int c4 = (idx & 63) << 2;
        *reinterpret_cast<float4*>(&Pt[row][c4]) =
            *reinterpret_cast<const float4*>(pooled + (size_t)(sbase + row) * NHID + c4);
    }
    __syncthreads();
    const int oc = (t & 31) << 2;
    const int sg = t >> 5;
    float a0x = 0.f, a0y = 0.f, a0z = 0.f, a0w = 0.f;
    float a1x = 0.f, a1y = 0.f, a1z = 0.f, a1w = 0.f;
#pragma unroll 4
    for (int k = 0; k < NHID; ++k) {
        const float4 w = *reinterpret_cast<const float4*>(Wout + (size_t)k * NOUT + oc);
        const float p0 = Pt[(sg << 1) + 0][k];
        const float p1 = Pt[(sg << 1) + 1][k];
        a0x = fmaf(p0, w.x, a0x); a0y = fmaf(p0, w.y, a0y);
        a0z = fmaf(p0, w.z, a0z); a0w = fmaf(p0, w.w, a0w);
        a1x = fmaf(p1, w.x, a1x); a1y = fmaf(p1, w.y, a1y);
        a1z = fmaf(p1, w.z, a1z); a1w = fmaf(p1, w.w, a1w);
    }
    *reinterpret_cast<float4*>(out + (size_t)(sbase + (sg << 1) + 0) * NOUT + oc) =
        make_float4(a0x, a0y, a0z, a0w);
    *reinterpret_cast<float4*>(out + (size_t)(sbase + (sg << 1) + 1) * NOUT + oc) =
        make_float4(a1x, a1y, a1z, a1w);
}

// ---------------------------------------------------------------------------
extern "C" void kernel_launch(void* const* d_in, const int* in_sizes, int n_in,
                              void* d_out, int out_size, void* d_ws, size_t ws_size,
                              hipStream_t stream)
{
    const float* emb  = (const float*)d_in[0];
    const float* Wv   = (const float*)d_in[1];
    const float* Wout = (const float*)d_in[2];
    const int*   map  = (const int*)d_in[3];
    float* out = (float*)d_out;

    char* ws = (char*)d_ws;
    float*    pooled = (float*)ws;                    // 10,240,000 B
    int*      start  = (int*)(ws + 10240000);         //     40,004 B
    _Float16* WfH    = (_Float16*)(ws + 10280064);    //     32,768 B
    _Float16* WfL    = (_Float16*)(ws + 10312832);    //     32,768 B

    wconv_kernel<<<8, 256, 0, stream>>>(Wv, WfH, WfL);
    bounds_kernel<<<(NV + 255) / 256, 256, 0, stream>>>(map, start);
    fused_kernel<<<FUSED_GRID, 256, 0, stream>>>(emb, WfH, WfL, start, pooled);
    out_kernel<<<NS / 16, 256, 0, stream>>>(pooled, Wout, out);
}

// Round 18
// 83.744 us; speedup vs baseline: 1.2344x; 1.2105x over previous
//
#include <hip/hip_runtime.h>

#define NV    500000
#define ND    64
#define NH    4
#define NHID  256
#define NS    10000
#define NOUT  128
#define GSAMP 4                 // samples per block
#define FUSED_GRID (NS / GSAMP) // 2500

typedef __attribute__((ext_vector_type(8))) _Float16 f16x8;
typedef __attribute__((ext_vector_type(4))) _Float16 f16x4;
typedef __attribute__((ext_vector_type(2))) __fp16   hf16x2;   // cvt_pkrtz result type
typedef __attribute__((ext_vector_type(4))) float    f32x4;

// ---------------------------------------------------------------------------
// Kernel W: write W_v as f16 MFMA fragments in exact lane order (hi only —
// R18 numerics: f16 quantization error on scores ~1.6e-2, well within budget).
// ---------------------------------------------------------------------------
__global__ __launch_bounds__(256) void wconv_kernel(
    const float* __restrict__ Wv, _Float16* __restrict__ WfH)
{
    const int tid  = blockIdx.x * 256 + threadIdx.x;  // 0..2047
    const int lane = tid & 63;
    const int slot = tid >> 6;        // 0..31
    const int ks   = slot & 1;
    const int jt   = (slot >> 1) & 3;
    const int h    = slot >> 3;
    const int vcol = lane & 15;
    const int g    = lane >> 4;
    const int j    = h * 64 + jt * 16 + vcol;
    const int kb   = ks * 32 + g * 8;
    f16x8 hv;
#pragma unroll
    for (int i = 0; i < 8; ++i)
        hv[i] = (_Float16)Wv[(size_t)(kb + i) * NHID + j];
    *reinterpret_cast<f16x8*>(WfH + ((size_t)slot << 9) + (lane << 3)) = hv;
}

// ---------------------------------------------------------------------------
// Kernel B: segment boundaries from the SORTED map.
// ---------------------------------------------------------------------------
__global__ void bounds_kernel(const int* __restrict__ map, int* __restrict__ start)
{
    const int v = blockIdx.x * blockDim.x + threadIdx.x;
    if (v >= NV) return;
    const int cur = map[v];
    if (v == 0) {
        for (int s = 0; s <= cur; ++s) start[s] = 0;
    } else {
        const int prev = map[v - 1];
        for (int s = prev + 1; s <= cur; ++s) start[s] = v;
    }
    if (v == NV - 1) {
        for (int s = cur + 1; s <= NS; ++s) start[s] = NV;
    }
}

// ---------------------------------------------------------------------------
// Fused: scores (f16 MFMA) -> online softmax -> PV MFMA pooling with
// k-permuted operands (pi(v) = (v&15)*4 + (v>>4) on BOTH sides; verified
// R15/R16/R17). R18: split-f16 removed (pure hi path) — score MFMAs 24->8
// per v-tile, EL array + lo-conversion deleted, W prologue halved, LDS 19 KB.
// ---------------------------------------------------------------------------
__global__ __launch_bounds__(256, 4) void fused_kernel(
    const float* __restrict__ emb,
    const _Float16* __restrict__ WfH,
    const int* __restrict__ start, float* __restrict__ pooled)
{
    __shared__ _Float16 EH[64 * 64];    // emb hi, row-major swizzled (8 KB)
    __shared__ _Float16 EHt[64 * 68];   // emb hi, d-major, v'-permuted, 136B rows (8.5 KB)
    __shared__ _Float16 ELDS[16][72];   // e-matrix, k-permuted, padded (2.25 KB)
    __shared__ float    rbuf[NH];       // per-head chunk rescale factors
    __shared__ float    lbuf[NH];       // per-head final denominators

    const int t    = threadIdx.x;
    const int lane = t & 63;
    const int h    = t >> 6;          // wave id == head (scores) == d-block (PV)
    const int vcol = lane & 15;
    const int g    = lane >> 4;

    // ---- W fragments for head h: coalesced 16B/lane loads ----
    f16x8 wh[4][2];
#pragma unroll
    for (int jt = 0; jt < 4; ++jt)
#pragma unroll
        for (int ks = 0; ks < 2; ++ks) {
            const int slot = ((h * 4 + jt) * 2 + ks);
            wh[jt][ks] = *reinterpret_cast<const f16x8*>(
                WfH + ((size_t)slot << 9) + (lane << 3));
        }

    // zero ELDS once (rows 4..15 / pad cols stay zero)
    for (int i = t; i < (16 * 72 * 2) / 4; i += 256)
        reinterpret_cast<unsigned*>(ELDS)[i] = 0u;

    const int s0   = blockIdx.x * GSAMP;
    const int srow = t >> 4;          // 0..15 (stage row base within chunk)
    const int sk4  = (t & 15) << 2;   // d base: 0..60
    const int woff = (srow << 7) + ((sk4 << 1) ^ ((srow & 7) << 4)); // EH byte

    // PV constants
    const int dpv  = (h << 4) + vcol;            // PV column d
    const int pvb  = dpv * 136 + (g << 4);       // eb0 byte base (b64-aligned)
    const int epos = ((lane & 15) << 2) + (lane >> 4);   // pi(lane)

    for (int si = 0; si < GSAMP; ++si) {
        const int s  = s0 + si;
        const int st = start[s];
        const int en = start[s + 1];
        if (st >= en) { pooled[(size_t)s * NHID + t] = 0.f; continue; }

        f32x4 acc = {0.f, 0.f, 0.f, 0.f};
        float m = -1e30f, l = 0.f;

        for (int c0 = st; c0 < en; c0 += 64) {
            const int C = min(64, en - c0);

            // ---- load 4 rows (named regs), convert to f16, stage EH/EHt ----
            const float4 z4 = make_float4(0.f, 0.f, 0.f, 0.f);
            float4 x0 = (srow      < C) ? *reinterpret_cast<const float4*>(emb + (size_t)(c0 + srow     ) * ND + sk4) : z4;
            float4 x1 = (srow + 16 < C) ? *reinterpret_cast<const float4*>(emb + (size_t)(c0 + srow + 16) * ND + sk4) : z4;
            float4 x2 = (srow + 32 < C) ? *reinterpret_cast<const float4*>(emb + (size_t)(c0 + srow + 32) * ND + sk4) : z4;
            float4 x3 = (srow + 48 < C) ? *reinterpret_cast<const float4*>(emb + (size_t)(c0 + srow + 48) * ND + sk4) : z4;

            f16x4 hv0, hv1, hv2, hv3;
#define CONV_ONE(X, HV, IT)                                                   \
            {                                                                 \
                const hf16x2 a01 = __builtin_amdgcn_cvt_pkrtz(X.x, X.y);      \
                const hf16x2 a23 = __builtin_amdgcn_cvt_pkrtz(X.z, X.w);      \
                HV[0] = (_Float16)a01[0]; HV[1] = (_Float16)a01[1];           \
                HV[2] = (_Float16)a23[0]; HV[3] = (_Float16)a23[1];           \
                *reinterpret_cast<f16x4*>((char*)EH + woff + (IT << 11)) = HV;\
            }
            CONV_ONE(x0, hv0, 0)
            CONV_ONE(x1, hv1, 1)
            CONV_ONE(x2, hv2, 2)
            CONV_ONE(x3, hv3, 3)
#undef CONV_ONE
            // EHt: per d (jj), the 4 it-values are consecutive v' = srow*4..+3
#pragma unroll
            for (int jj = 0; jj < 4; ++jj) {
                const int d = sk4 + jj;
                f16x4 w4;
                w4[0] = hv0[jj]; w4[1] = hv1[jj]; w4[2] = hv2[jj]; w4[3] = hv3[jj];
                const int ob = d * 136 + (srow << 3);     // b64-aligned, bank-rotated
                *reinterpret_cast<f16x4*>((char*)EHt + ob) = w4;
            }
            __syncthreads();   // bar1: stage visible

            // ---- scores for head h; only occupied v-tiles (uniform guard) ---
            float sv[4];
            __builtin_amdgcn_s_setprio(1);
#pragma unroll
            for (int vt = 0; vt < 4; ++vt) {
                float sreg = 0.f;
                if ((vt << 4) < C) {   // wave-uniform (C from SGPRs)
                    const int row = (vt << 4) + vcol;
                    const int rb  = row << 7;
                    const int sw  = (row & 7) << 4;
                    const f16x8 bh0 = *reinterpret_cast<const f16x8*>(
                        (const char*)EH + rb + (((g << 4)) ^ sw));
                    const f16x8 bh1 = *reinterpret_cast<const f16x8*>(
                        (const char*)EH + rb + ((64 | (g << 4)) ^ sw));
#pragma unroll
                    for (int jt = 0; jt < 4; ++jt) {
                        f32x4 a4 = {0.f, 0.f, 0.f, 0.f};
                        a4 = __builtin_amdgcn_mfma_f32_16x16x32_f16(wh[jt][0], bh0, a4, 0, 0, 0);
                        a4 = __builtin_amdgcn_mfma_f32_16x16x32_f16(wh[jt][1], bh1, a4, 0, 0, 0);
                        sreg += a4[0]*a4[0] + a4[1]*a4[1] + a4[2]*a4[2] + a4[3]*a4[3];
                    }
                    sreg += __shfl_xor(sreg, 16, 64);
                    sreg += __shfl_xor(sreg, 32, 64);
                }
                sv[vt] = sreg;
            }
            __builtin_amdgcn_s_setprio(0);

            // lane's own score (v = lane): static cndmask select
            const float scA = (lane & 16) ? sv[1] : sv[0];
            const float scB = (lane & 16) ? sv[3] : sv[2];
            const float scO = (lane & 32) ? scB : scA;

            // ---- online softmax update (wave-local, head h) ----
            const float sc = (lane < C) ? scO : -1e30f;
            float cmax = sc;
#pragma unroll
            for (int off = 1; off < 64; off <<= 1)
                cmax = fmaxf(cmax, __shfl_xor(cmax, off, 64));
            const float mn = fmaxf(m, cmax);
            const float r  = __expf(m - mn);
            const float e  = (lane < C) ? __expf(sc - mn) : 0.f;
            float csum = e;
#pragma unroll
            for (int off = 1; off < 64; off <<= 1)
                csum += __shfl_xor(csum, off, 64);
            l = l * r + csum;
            m = mn;

            // publish e (f16, k-permuted) and this head's rescale factor
            ELDS[h][epos] = (_Float16)e;
            if (lane == 0) rbuf[h] = r;
            __syncthreads();   // bar2: e + EHt + rbuf visible

            // ---- PV: C[m=head][n=d] += e x emb; rescale row m by r_m ----
            const float rb0 = rbuf[0], rb1 = rbuf[1], rb2 = rbuf[2], rb3 = rbuf[3];
            const f16x8 ea0 = *reinterpret_cast<const f16x8*>(&ELDS[vcol][g << 3]);
            const f16x8 ea1 = *reinterpret_cast<const f16x8*>(&ELDS[vcol][(g << 3) + 32]);
            const f16x4 b0lo = *reinterpret_cast<const f16x4*>((const char*)EHt + pvb);
            const f16x4 b0hi = *reinterpret_cast<const f16x4*>((const char*)EHt + pvb + 8);
            const f16x4 b1lo = *reinterpret_cast<const f16x4*>((const char*)EHt + pvb + 64);
            const f16x4 b1hi = *reinterpret_cast<const f16x4*>((const char*)EHt + pvb + 72);
            f16x8 eb0, eb1;
            eb0[0]=b0lo[0]; eb0[1]=b0lo[1]; eb0[2]=b0lo[2]; eb0[3]=b0lo[3];
            eb0[4]=b0hi[0]; eb0[5]=b0hi[1]; eb0[6]=b0hi[2]; eb0[7]=b0hi[3];
            eb1[0]=b1lo[0]; eb1[1]=b1lo[1]; eb1[2]=b1lo[2]; eb1[3]=b1lo[3];
            eb1[4]=b1hi[0]; eb1[5]=b1hi[1]; eb1[6]=b1hi[2]; eb1[7]=b1hi[3];
            acc[0] *= rb0; acc[1] *= rb1; acc[2] *= rb2; acc[3] *= rb3;
            acc = __builtin_amdgcn_mfma_f32_16x16x32_f16(ea0, eb0, acc, 0, 0, 0);
            acc = __builtin_amdgcn_mfma_f32_16x16x32_f16(ea1, eb1, acc, 0, 0, 0);
            __syncthreads();   // bar3: PV reads done before next stage
        }

        // ---- publish per-head denominators, then write pooled ----
        if (lane == 0) lbuf[h] = l;
        __syncthreads();
        if (g == 0) {
#pragma unroll
            for (int rr = 0; rr < 4; ++rr)
                pooled[(size_t)s * NHID + rr * 64 + (h << 4) + vcol] =
                    acc[rr] / lbuf[rr];
        }
    }
}

// ---------------------------------------------------------------------------
// Kernel D: out = pooled @ W_out
// ---------------------------------------------------------------------------
__global__ __launch_bounds__(256) void out_kernel(
    const float* __restrict__ pooled, const float* __restrict__ Wout,
    float* __restrict__ out)
{
    __shared__ float Pt[16][260];
    const int t = threadIdx.x;
    const int sbase = blockIdx.x << 4;
#pragma unroll
    for (int it = 0; it < 4; ++it) {
        const int idx = t + (it << 8);
        const int row = idx >> 6;
        const int c4 = (idx & 63) << 2;
        *reinterpret_cast<float4*>(&Pt[row][c4]) =
            *reinterpret_cast<const float4*>(pooled + (size_t)(sbase + row) * NHID + c4);
    }
    __syncthreads();
    const int oc = (t & 31) << 2;
    const int sg = t >> 5;
    float a0x = 0.f, a0y = 0.f, a0z = 0.f, a0w = 0.f;
    float a1x = 0.f, a1y = 0.f, a1z = 0.f, a1w = 0.f;
#pragma unroll 4
    for (int k = 0; k < NHID; ++k) {
        const float4 w = *reinterpret_cast<const float4*>(Wout + (size_t)k * NOUT + oc);
        const float p0 = Pt[(sg << 1) + 0][k];
        const float p1 = Pt[(sg << 1) + 1][k];
        a0x = fmaf(p0, w.x, a0x); a0y = fmaf(p0, w.y, a0y);
        a0z = fmaf(p0, w.z, a0z); a0w = fmaf(p0, w.w, a0w);
        a1x = fmaf(p1, w.x, a1x); a1y = fmaf(p1, w.y, a1y);
        a1z = fmaf(p1, w.z, a1z); a1w = fmaf(p1, w.w, a1w);
    }
    *reinterpret_cast<float4*>(out + (size_t)(sbase + (sg << 1) + 0) * NOUT + oc) =
        make_float4(a0x, a0y, a0z, a0w);
    *reinterpret_cast<float4*>(out + (size_t)(sbase + (sg << 1) + 1) * NOUT + oc) =
        make_float4(a1x, a1y, a1z, a1w);
}

// ---------------------------------------------------------------------------
extern "C" void kernel_launch(void* const* d_in, const int* in_sizes, int n_in,
                              void* d_out, int out_size, void* d_ws, size_t ws_size,
                              hipStream_t stream)
{
    const float* emb  = (const float*)d_in[0];
    const float* Wv   = (const float*)d_in[1];
    const float* Wout = (const float*)d_in[2];
    const int*   map  = (const int*)d_in[3];
    float* out = (float*)d_out;

    char* ws = (char*)d_ws;
    float*    pooled = (float*)ws;                    // 10,240,000 B
    int*      start  = (int*)(ws + 10240000);         //     40,004 B
    _Float16* WfH    = (_Float16*)(ws + 10280064);    //     32,768 B

    wconv_kernel<<<8, 256, 0, stream>>>(Wv, WfH);
    bounds_kernel<<<(NV + 255) / 256, 256, 0, stream>>>(map, start);
    fused_kernel<<<FUSED_GRID, 256, 0, stream>>>(emb, WfH, start, pooled);
    out_kernel<<<NS / 16, 256, 0, stream>>>(pooled, Wout, out);
}

// Round 19
// 78.944 us; speedup vs baseline: 1.3095x; 1.0608x over previous
//
#include <hip/hip_runtime.h>

#define NV    500000
#define ND    64
#define NH    4
#define NHID  256
#define NS    10000
#define NOUT  128
#define GSAMP 4                 // samples per block
#define FUSED_GRID (NS / GSAMP) // 2500
#define EHT_BYTES (64 * 68 * 2) // one EHt buffer: 8704 B

typedef __attribute__((ext_vector_type(8))) _Float16 f16x8;
typedef __attribute__((ext_vector_type(4))) _Float16 f16x4;
typedef __attribute__((ext_vector_type(2))) __fp16   hf16x2;   // cvt_pkrtz result type
typedef __attribute__((ext_vector_type(4))) float    f32x4;

// ---------------------------------------------------------------------------
// Kernel W: write W_v as f16 MFMA fragments in exact lane order (hi only).
// ---------------------------------------------------------------------------
__global__ __launch_bounds__(256) void wconv_kernel(
    const float* __restrict__ Wv, _Float16* __restrict__ WfH)
{
    const int tid  = blockIdx.x * 256 + threadIdx.x;  // 0..2047
    const int lane = tid & 63;
    const int slot = tid >> 6;        // 0..31
    const int ks   = slot & 1;
    const int jt   = (slot >> 1) & 3;
    const int h    = slot >> 3;
    const int vcol = lane & 15;
    const int g    = lane >> 4;
    const int j    = h * 64 + jt * 16 + vcol;
    const int kb   = ks * 32 + g * 8;
    f16x8 hv;
#pragma unroll
    for (int i = 0; i < 8; ++i)
        hv[i] = (_Float16)Wv[(size_t)(kb + i) * NHID + j];
    *reinterpret_cast<f16x8*>(WfH + ((size_t)slot << 9) + (lane << 3)) = hv;
}

// ---------------------------------------------------------------------------
// Kernel B: segment boundaries from the SORTED map.
// ---------------------------------------------------------------------------
__global__ void bounds_kernel(const int* __restrict__ map, int* __restrict__ start)
{
    const int v = blockIdx.x * blockDim.x + threadIdx.x;
    if (v >= NV) return;
    const int cur = map[v];
    if (v == 0) {
        for (int s = 0; s <= cur; ++s) start[s] = 0;
    } else {
        const int prev = map[v - 1];
        for (int s = prev + 1; s <= cur; ++s) start[s] = v;
    }
    if (v == NV - 1) {
        for (int s = cur + 1; s <= NS; ++s) start[s] = NV;
    }
}

// ---------------------------------------------------------------------------
// Fused, chunk-pipelined (R19): flat chunk stream across the block's GSAMP
// samples; 2 barriers/chunk. Next chunk's global loads are issued BEFORE
// barA and consumed (convert + stage into EH / EHt[p^1]) after PV, so HBM
// latency hides under barA+PV. EHt double-buffered; EH/ELDS/rbuf/lbuf single
// (dependency-audited against the two barriers). Numerics identical to R18.
// ---------------------------------------------------------------------------
__global__ __launch_bounds__(256, 4) void fused_kernel(
    const float* __restrict__ emb,
    const _Float16* __restrict__ WfH,
    const int* __restrict__ start, float* __restrict__ pooled)
{
    __shared__ _Float16 EH[64 * 64];      // emb hi, row-major swizzled (8 KB)
    __shared__ _Float16 EHt[2][64 * 68];  // emb hi, d-major, v'-permuted (2x8.5 KB)
    __shared__ _Float16 ELDS[16][72];     // e-matrix, k-permuted, padded (2.25 KB)
    __shared__ float    rbuf[NH];         // per-head chunk rescale factors
    __shared__ float    lbuf[NH];         // per-head final denominators

    const int t    = threadIdx.x;
    const int lane = t & 63;
    const int h    = t >> 6;          // wave id == head (scores) == d-block (PV)
    const int vcol = lane & 15;
    const int g    = lane >> 4;

    // ---- W fragments for head h: coalesced 16B/lane loads ----
    f16x8 wh[4][2];
#pragma unroll
    for (int jt = 0; jt < 4; ++jt)
#pragma unroll
        for (int ks = 0; ks < 2; ++ks) {
            const int slot = ((h * 4 + jt) * 2 + ks);
            wh[jt][ks] = *reinterpret_cast<const f16x8*>(
                WfH + ((size_t)slot << 9) + (lane << 3));
        }

    // zero ELDS once (rows 4..15 / pad cols stay zero)
    for (int i = t; i < (16 * 72 * 2) / 4; i += 256)
        reinterpret_cast<unsigned*>(ELDS)[i] = 0u;

    const int s0   = blockIdx.x * GSAMP;
    const int sEnd = s0 + GSAMP;
    const int srow = t >> 4;          // 0..15 (stage row base within chunk)
    const int sk4  = (t & 15) << 2;   // d base: 0..60
    const int woff = (srow << 7) + ((sk4 << 1) ^ ((srow & 7) << 4)); // EH byte

    // PV constants
    const int dpv  = (h << 4) + vcol;            // PV column d
    const int pvb  = dpv * 136 + (g << 4);       // eb byte base (b64-aligned)
    const int epos = ((lane & 15) << 2) + (lane >> 4);   // pi(lane)

    // ---- find first non-empty sample (zeros for empties) ----
    int s = s0, st = 0, en = 0;
    for (;;) {
        if (s == sEnd) break;
        st = start[s]; en = start[s + 1];
        if (st < en) break;
        pooled[(size_t)s * NHID + t] = 0.f;
        ++s;
    }
    if (s == sEnd) return;

    const float4 z4 = make_float4(0.f, 0.f, 0.f, 0.f);
    int c0 = st;
    int p  = 0;

#define CONV_STAGE(X0, X1, X2, X3, CC, PBUF)                                  \
    {                                                                         \
        const float4 y0 = (srow      < (CC)) ? (X0) : z4;                     \
        const float4 y1 = (srow + 16 < (CC)) ? (X1) : z4;                     \
        const float4 y2 = (srow + 32 < (CC)) ? (X2) : z4;                     \
        const float4 y3 = (srow + 48 < (CC)) ? (X3) : z4;                     \
        f16x4 hv0, hv1, hv2, hv3;                                             \
        {                                                                     \
            const hf16x2 a01 = __builtin_amdgcn_cvt_pkrtz(y0.x, y0.y);        \
            const hf16x2 a23 = __builtin_amdgcn_cvt_pkrtz(y0.z, y0.w);        \
            hv0[0] = (_Float16)a01[0]; hv0[1] = (_Float16)a01[1];             \
            hv0[2] = (_Float16)a23[0]; hv0[3] = (_Float16)a23[1];             \
            const hf16x2 b01 = __builtin_amdgcn_cvt_pkrtz(y1.x, y1.y);        \
            const hf16x2 b23 = __builtin_amdgcn_cvt_pkrtz(y1.z, y1.w);        \
            hv1[0] = (_Float16)b01[0]; hv1[1] = (_Float16)b01[1];             \
            hv1[2] = (_Float16)b23[0]; hv1[3] = (_Float16)b23[1];             \
            const hf16x2 c01 = __builtin_amdgcn_cvt_pkrtz(y2.x, y2.y);        \
            const hf16x2 c23 = __builtin_amdgcn_cvt_pkrtz(y2.z, y2.w);        \
            hv2[0] = (_Float16)c01[0]; hv2[1] = (_Float16)c01[1];             \
            hv2[2] = (_Float16)c23[0]; hv2[3] = (_Float16)c23[1];             \
            const hf16x2 d01 = __builtin_amdgcn_cvt_pkrtz(y3.x, y3.y);        \
            const hf16x2 d23 = __builtin_amdgcn_cvt_pkrtz(y3.z, y3.w);        \
            hv3[0] = (_Float16)d01[0]; hv3[1] = (_Float16)d01[1];             \
            hv3[2] = (_Float16)d23[0]; hv3[3] = (_Float16)d23[1];             \
        }                                                                     \
        *reinterpret_cast<f16x4*>((char*)EH + woff)             = hv0;        \
        *reinterpret_cast<f16x4*>((char*)EH + woff + (1 << 11)) = hv1;        \
        *reinterpret_cast<f16x4*>((char*)EH + woff + (2 << 11)) = hv2;        \
        *reinterpret_cast<f16x4*>((char*)EH + woff + (3 << 11)) = hv3;        \
        _Pragma("unroll")                                                     \
        for (int jj = 0; jj < 4; ++jj) {                                      \
            const int d = sk4 + jj;                                           \
            f16x4 w4;                                                         \
            w4[0] = hv0[jj]; w4[1] = hv1[jj]; w4[2] = hv2[jj]; w4[3] = hv3[jj];\
            *reinterpret_cast<f16x4*>((char*)EHt[(PBUF)] + d * 136 + (srow << 3)) = w4; \
        }                                                                     \
    }

    // ---- prologue: stage first chunk into EH + EHt[0] ----
    {
        const int C = min(64, en - c0);
        float4 x0 = (srow      < C) ? *reinterpret_cast<const float4*>(emb + (size_t)(c0 + srow     ) * ND + sk4) : z4;
        float4 x1 = (srow + 16 < C) ? *reinterpret_cast<const float4*>(emb + (size_t)(c0 + srow + 16) * ND + sk4) : z4;
        float4 x2 = (srow + 32 < C) ? *reinterpret_cast<const float4*>(emb + (size_t)(c0 + srow + 32) * ND + sk4) : z4;
        float4 x3 = (srow + 48 < C) ? *reinterpret_cast<const float4*>(emb + (size_t)(c0 + srow + 48) * ND + sk4) : z4;
        CONV_STAGE(x0, x1, x2, x3, C, 0)
    }
    __syncthreads();

    f32x4 acc = {0.f, 0.f, 0.f, 0.f};
    float m = -1e30f, l = 0.f;

    for (;;) {
        const int C = min(64, en - c0);

        // ---- scores for head h; only occupied v-tiles (uniform guard) ----
        float sv[4];
        __builtin_amdgcn_s_setprio(1);
#pragma unroll
        for (int vt = 0; vt < 4; ++vt) {
            float sreg = 0.f;
            if ((vt << 4) < C) {   // wave-uniform
                const int row = (vt << 4) + vcol;
                const int rb  = row << 7;
                const int sw  = (row & 7) << 4;
                const f16x8 bh0 = *reinterpret_cast<const f16x8*>(
                    (const char*)EH + rb + (((g << 4)) ^ sw));
                const f16x8 bh1 = *reinterpret_cast<const f16x8*>(
                    (const char*)EH + rb + ((64 | (g << 4)) ^ sw));
#pragma unroll
                for (int jt = 0; jt < 4; ++jt) {
                    f32x4 a4 = {0.f, 0.f, 0.f, 0.f};
                    a4 = __builtin_amdgcn_mfma_f32_16x16x32_f16(wh[jt][0], bh0, a4, 0, 0, 0);
                    a4 = __builtin_amdgcn_mfma_f32_16x16x32_f16(wh[jt][1], bh1, a4, 0, 0, 0);
                    sreg += a4[0]*a4[0] + a4[1]*a4[1] + a4[2]*a4[2] + a4[3]*a4[3];
                }
                sreg += __shfl_xor(sreg, 16, 64);
                sreg += __shfl_xor(sreg, 32, 64);
            }
            sv[vt] = sreg;
        }
        __builtin_amdgcn_s_setprio(0);

        const float scA = (lane & 16) ? sv[1] : sv[0];
        const float scB = (lane & 16) ? sv[3] : sv[2];
        const float scO = (lane & 32) ? scB : scA;

        // ---- online softmax update (wave-local, head h) ----
        const float sc = (lane < C) ? scO : -1e30f;
        float cmax = sc;
#pragma unroll
        for (int off = 1; off < 64; off <<= 1)
            cmax = fmaxf(cmax, __shfl_xor(cmax, off, 64));
        const float mn = fmaxf(m, cmax);
        const float r  = __expf(m - mn);
        const float e  = (lane < C) ? __expf(sc - mn) : 0.f;
        float csum = e;
#pragma unroll
        for (int off = 1; off < 64; off <<= 1)
            csum += __shfl_xor(csum, off, 64);
        l = l * r + csum;
        m = mn;

        const bool lastOfSample = (c0 + 64 >= en);

        // ---- locate next chunk (zeros for skipped empty samples) ----
        int ns = s, nc0 = c0 + 64, nen = en;
        if (lastOfSample) {
            ns = s + 1; nc0 = 0; nen = 0;
            while (ns < sEnd) {
                const int a = start[ns], b = start[ns + 1];
                if (a < b) { nc0 = a; nen = b; break; }
                pooled[(size_t)ns * NHID + t] = 0.f;
                ++ns;
            }
        }
        const bool hasNext = (ns < sEnd) && (nc0 < nen);

        // ---- publish e (f16, k-permuted), r, (l if last) ----
        ELDS[h][epos] = (_Float16)e;
        if (lane == 0) { rbuf[h] = r; if (lastOfSample) lbuf[h] = l; }

        // ---- issue next chunk's global loads (consumed after PV) ----
        float4 x0 = z4, x1 = z4, x2 = z4, x3 = z4;
        int nC = 0;
        if (hasNext) {
            nC = min(64, nen - nc0);
            if (srow      < nC) x0 = *reinterpret_cast<const float4*>(emb + (size_t)(nc0 + srow     ) * ND + sk4);
            if (srow + 16 < nC) x1 = *reinterpret_cast<const float4*>(emb + (size_t)(nc0 + srow + 16) * ND + sk4);
            if (srow + 32 < nC) x2 = *reinterpret_cast<const float4*>(emb + (size_t)(nc0 + srow + 32) * ND + sk4);
            if (srow + 48 < nC) x3 = *reinterpret_cast<const float4*>(emb + (size_t)(nc0 + srow + 48) * ND + sk4);
        }

        __syncthreads();   // barA: e/rbuf/lbuf visible; EH reads done

        // ---- PV: C[m=head][n=d] += e x emb; rescale row m by r_m ----
        {
            const float rb0 = rbuf[0], rb1 = rbuf[1], rb2 = rbuf[2], rb3 = rbuf[3];
            const f16x8 ea0 = *reinterpret_cast<const f16x8*>(&ELDS[vcol][g << 3]);
            const f16x8 ea1 = *reinterpret_cast<const f16x8*>(&ELDS[vcol][(g << 3) + 32]);
            const char* base = (const char*)EHt[p];
            const f16x4 b0lo = *reinterpret_cast<const f16x4*>(base + pvb);
            const f16x4 b0hi = *reinterpret_cast<const f16x4*>(base + pvb + 8);
            const f16x4 b1lo = *reinterpret_cast<const f16x4*>(base + pvb + 64);
            const f16x4 b1hi = *reinterpret_cast<const f16x4*>(base + pvb + 72);
            f16x8 eb0, eb1;
            eb0[0]=b0lo[0]; eb0[1]=b0lo[1]; eb0[2]=b0lo[2]; eb0[3]=b0lo[3];
            eb0[4]=b0hi[0]; eb0[5]=b0hi[1]; eb0[6]=b0hi[2]; eb0[7]=b0hi[3];
            eb1[0]=b1lo[0]; eb1[1]=b1lo[1]; eb1[2]=b1lo[2]; eb1[3]=b1lo[3];
            eb1[4]=b1hi[0]; eb1[5]=b1hi[1]; eb1[6]=b1hi[2]; eb1[7]=b1hi[3];
            acc[0] *= rb0; acc[1] *= rb1; acc[2] *= rb2; acc[3] *= rb3;
            acc = __builtin_amdgcn_mfma_f32_16x16x32_f16(ea0, eb0, acc, 0, 0, 0);
            acc = __builtin_amdgcn_mfma_f32_16x16x32_f16(ea1, eb1, acc, 0, 0, 0);
        }

        // ---- convert + stage next chunk into EH + EHt[p^1] ----
        if (hasNext)
            CONV_STAGE(x0, x1, x2, x3, nC, p ^ 1)

        // ---- sample end: write out + reset ----
        if (lastOfSample) {
            if (g == 0) {
#pragma unroll
                for (int rr = 0; rr < 4; ++rr)
                    pooled[(size_t)s * NHID + rr * 64 + (h << 4) + vcol] =
                        acc[rr] / lbuf[rr];
            }
            acc[0] = acc[1] = acc[2] = acc[3] = 0.f;
            m = -1e30f; l = 0.f;
            s = ns; c0 = nc0; en = nen;
        } else {
            c0 = nc0;
        }

        if (!hasNext) break;
        __syncthreads();   // barB: stage visible; PV reads done
        p ^= 1;
    }
#undef CONV_STAGE
}

// ---------------------------------------------------------------------------
// Kernel D: out = pooled @ W_out
// ---------------------------------------------------------------------------
__global__ __launch_bounds__(256) void out_kernel(
    const float* __restrict__ pooled, const float* __restrict__ Wout,
    float* __restrict__ out)
{
    __shared__ float Pt[16][260];
    const int t = threadIdx.x;
    const int sbase = blockIdx.x << 4;
#pragma unroll
    for (int it = 0; it < 4; ++it) {
        const int idx = t + (it << 8);
        const int row = idx >> 6;
        const int c4 = (idx & 63) << 2;
        *reinterpret_cast<float4*>(&Pt[row][c4]) =
            *reinterpret_cast<const float4*>(pooled + (size_t)(sbase + row) * NHID + c4);
    }
    __syncthreads();
    const int oc = (t & 31) << 2;
    const int sg = t >> 5;
    float a0x = 0.f, a0y = 0.f, a0z = 0.f, a0w = 0.f;
    float a1x = 0.f, a1y = 0.f, a1z = 0.f, a1w = 0.f;
#pragma unroll 4
    for (int k = 0; k < NHID; ++k) {
        const float4 w = *reinterpret_cast<const float4*>(Wout + (size_t)k * NOUT + oc);
        const float p0 = Pt[(sg << 1) + 0][k];
        const float p1 = Pt[(sg << 1) + 1][k];
        a0x = fmaf(p0, w.x, a0x); a0y = fmaf(p0, w.y, a0y);
        a0z = fmaf(p0, w.z, a0z); a0w = fmaf(p0, w.w, a0w);
        a1x = fmaf(p1, w.x, a1x); a1y = fmaf(p1, w.y, a1y);
        a1z = fmaf(p1, w.z, a1z); a1w = fmaf(p1, w.w, a1w);
    }
    *reinterpret_cast<float4*>(out + (size_t)(sbase + (sg << 1) + 0) * NOUT + oc) =
        make_float4(a0x, a0y, a0z, a0w);
    *reinterpret_cast<float4*>(out + (size_t)(sbase + (sg << 1) + 1) * NOUT + oc) =
        make_float4(a1x, a1y, a1z, a1w);
}

// ---------------------------------------------------------------------------
extern "C" void kernel_launch(void* const* d_in, const int* in_sizes, int n_in,
                              void* d_out, int out_size, void* d_ws, size_t ws_size,
                              hipStream_t stream)
{
    const float* emb  = (const float*)d_in[0];
    const float* Wv   = (const float*)d_in[1];
    const float* Wout = (const float*)d_in[2];
    const int*   map  = (const int*)d_in[3];
    float* out = (float*)d_out;

    char* ws = (char*)d_ws;
    float*    pooled = (float*)ws;                    // 10,240,000 B
    int*      start  = (int*)(ws + 10240000);         //     40,004 B
    _Float16* WfH    = (_Float16*)(ws + 10280064);    //     32,768 B

    wconv_kernel<<<8, 256, 0, stream>>>(Wv, WfH);
    bounds_kernel<<<(NV + 255) / 256, 256, 0, stream>>>(map, start);
    fused_kernel<<<FUSED_GRID, 256, 0, stream>>>(emb, WfH, start, pooled);
    out_kernel<<<NS / 16, 256, 0, stream>>>(pooled, Wout, out);
}

// Round 20
// 56.308 us; speedup vs baseline: 1.8359x; 1.4020x over previous
//
#include <hip/hip_runtime.h>

#define NV    500000
#define ND    64
#define NH    4
#define NHID  256
#define NS    10000
#define NOUT  128
#define GSAMP 6                                // samples per block
#define FUSED_GRID ((NS + GSAMP - 1) / GSAMP)  // 1667
#define BOUNDS_BLOCKS ((NV + 255) / 256)       // 1954
#define PREP_GRID (24 + BOUNDS_BLOCKS)

typedef __attribute__((ext_vector_type(8))) _Float16 f16x8;
typedef __attribute__((ext_vector_type(4))) _Float16 f16x4;
typedef __attribute__((ext_vector_type(2))) __fp16   hf16x2;   // cvt_pkrtz result type
typedef __attribute__((ext_vector_type(4))) float    f32x4;

// ---------------------------------------------------------------------------
// Prep kernel (single launch):
//   blocks [0,8):   W_v -> f16 A-fragments (lane order), as R18's wconv
//   blocks [8,24):  W_out -> f16 B-fragments (lane order)
//   blocks [24,..): segment boundaries from the SORTED map
// ---------------------------------------------------------------------------
__global__ __launch_bounds__(256) void prep_kernel(
    const float* __restrict__ Wv, const float* __restrict__ Wout,
    const int* __restrict__ map,
    _Float16* __restrict__ WfH, _Float16* __restrict__ Wfout,
    int* __restrict__ start)
{
    const int b = blockIdx.x;
    const int t = threadIdx.x;
    if (b < 8) {
        const int tid  = b * 256 + t;     // 0..2047
        const int lane = tid & 63;
        const int slot = tid >> 6;        // 0..31
        const int ks   = slot & 1;
        const int jt   = (slot >> 1) & 3;
        const int h    = slot >> 3;
        const int j    = h * 64 + jt * 16 + (lane & 15);
        const int kb   = ks * 32 + (lane >> 4) * 8;
        f16x8 hv;
#pragma unroll
        for (int i = 0; i < 8; ++i)
            hv[i] = (_Float16)Wv[(size_t)(kb + i) * NHID + j];
        *reinterpret_cast<f16x8*>(WfH + ((size_t)slot << 9) + (lane << 3)) = hv;
    } else if (b < 24) {
        const int tid2 = (b - 8) * 256 + t;   // 0..4095
        const int lane = tid2 & 63;
        const int slot = tid2 >> 6;           // 0..63 = nt*8 + ks
        const int ks   = slot & 7;
        const int nt   = slot >> 3;
        const int n    = (nt << 4) + (lane & 15);
        const int kb   = (ks << 5) + ((lane >> 4) << 3);
        f16x8 hv;
#pragma unroll
        for (int i = 0; i < 8; ++i)
            hv[i] = (_Float16)Wout[(size_t)(kb + i) * NOUT + n];
        *reinterpret_cast<f16x8*>(Wfout + ((size_t)slot << 9) + (lane << 3)) = hv;
    } else {
        const int v = (b - 24) * 256 + t;
        if (v >= NV) return;
        const int cur = map[v];
        if (v == 0) {
            for (int s = 0; s <= cur; ++s) start[s] = 0;
        } else {
            const int prev = map[v - 1];
            for (int s = prev + 1; s <= cur; ++s) start[s] = v;
        }
        if (v == NV - 1) {
            for (int s = cur + 1; s <= NS; ++s) start[s] = NV;
        }
    }
}

// ---------------------------------------------------------------------------
// Fused (R20): chunk-pipelined scores->softmax->PV (R19 structure, verified)
// PLUS fused output projection: normalized pooled rows collected in PFL
// (f16, LDS) at sample finalize; after the chunk loop one barrier, then
// out[sample][:] = PFL @ W_out via 16 MFMAs/wave. pooled buffer and
// out_kernel deleted. Fragment mappings identical to verified paths.
// ---------------------------------------------------------------------------
__global__ __launch_bounds__(256, 4) void fused_kernel(
    const float* __restrict__ emb,
    const _Float16* __restrict__ WfH, const _Float16* __restrict__ Wfout,
    const int* __restrict__ start, float* __restrict__ out)
{
    __shared__ _Float16 EH[64 * 64];      // emb hi, row-major swizzled (8 KB)
    __shared__ _Float16 EHt[2][64 * 68];  // emb hi, d-major, v'-permuted (2x8.5 KB)
    __shared__ _Float16 ELDS[16][72];     // e-matrix, k-permuted, padded (2.25 KB)
    __shared__ _Float16 PFL[16][264];     // pooled rows (f16), padded (8.25 KB)
    __shared__ float    rbuf[NH];         // per-head chunk rescale factors
    __shared__ float    lbuf[NH];         // per-head final denominators

    const int t    = threadIdx.x;
    const int lane = t & 63;
    const int h    = t >> 6;          // wave id == head (scores) == d-block (PV)
    const int vcol = lane & 15;
    const int g    = lane >> 4;

    // ---- W fragments for head h: coalesced 16B/lane loads ----
    f16x8 wh[4][2];
#pragma unroll
    for (int jt = 0; jt < 4; ++jt)
#pragma unroll
        for (int ks = 0; ks < 2; ++ks) {
            const int slot = ((h * 4 + jt) * 2 + ks);
            wh[jt][ks] = *reinterpret_cast<const f16x8*>(
                WfH + ((size_t)slot << 9) + (lane << 3));
        }

    // zero ELDS (rows 4..15 / pads stay zero) and PFL (empty samples stay 0)
    for (int i = t; i < (16 * 72 * 2) / 4; i += 256)
        reinterpret_cast<unsigned*>(ELDS)[i] = 0u;
    for (int i = t; i < (16 * 264 * 2) / 4; i += 256)
        reinterpret_cast<unsigned*>(PFL)[i] = 0u;
    __syncthreads();   // PFL zero visible before any finalize writes

    const int s0   = blockIdx.x * GSAMP;
    const int sEnd = (s0 + GSAMP < NS) ? (s0 + GSAMP) : NS;
    const int srow = t >> 4;          // 0..15 (stage row base within chunk)
    const int sk4  = (t & 15) << 2;   // d base: 0..60
    const int woff = (srow << 7) + ((sk4 << 1) ^ ((srow & 7) << 4)); // EH byte

    // PV constants
    const int dpv  = (h << 4) + vcol;            // PV column d
    const int pvb  = dpv * 136 + (g << 4);       // eb byte base (b64-aligned)
    const int epos = ((lane & 15) << 2) + (lane >> 4);   // pi(lane)

    // ---- find first non-empty sample ----
    int s = s0, st = 0, en = 0;
    while (s < sEnd) {
        st = start[s]; en = start[s + 1];
        if (st < en) break;
        ++s;   // empty: PFL row stays zero -> out row = 0 from projection
    }

    const float4 z4 = make_float4(0.f, 0.f, 0.f, 0.f);

#define CONV_STAGE(X0, X1, X2, X3, CC, PBUF)                                  \
    {                                                                         \
        const float4 y0 = (srow      < (CC)) ? (X0) : z4;                     \
        const float4 y1 = (srow + 16 < (CC)) ? (X1) : z4;                     \
        const float4 y2 = (srow + 32 < (CC)) ? (X2) : z4;                     \
        const float4 y3 = (srow + 48 < (CC)) ? (X3) : z4;                     \
        f16x4 hv0, hv1, hv2, hv3;                                             \
        {                                                                     \
            const hf16x2 a01 = __builtin_amdgcn_cvt_pkrtz(y0.x, y0.y);        \
            const hf16x2 a23 = __builtin_amdgcn_cvt_pkrtz(y0.z, y0.w);        \
            hv0[0] = (_Float16)a01[0]; hv0[1] = (_Float16)a01[1];             \
            hv0[2] = (_Float16)a23[0]; hv0[3] = (_Float16)a23[1];             \
            const hf16x2 b01 = __builtin_amdgcn_cvt_pkrtz(y1.x, y1.y);        \
            const hf16x2 b23 = __builtin_amdgcn_cvt_pkrtz(y1.z, y1.w);        \
            hv1[0] = (_Float16)b01[0]; hv1[1] = (_Float16)b01[1];             \
            hv1[2] = (_Float16)b23[0]; hv1[3] = (_Float16)b23[1];             \
            const hf16x2 c01 = __builtin_amdgcn_cvt_pkrtz(y2.x, y2.y);        \
            const hf16x2 c23 = __builtin_amdgcn_cvt_pkrtz(y2.z, y2.w);        \
            hv2[0] = (_Float16)c01[0]; hv2[1] = (_Float16)c01[1];             \
            hv2[2] = (_Float16)c23[0]; hv2[3] = (_Float16)c23[1];             \
            const hf16x2 d01 = __builtin_amdgcn_cvt_pkrtz(y3.x, y3.y);        \
            const hf16x2 d23 = __builtin_amdgcn_cvt_pkrtz(y3.z, y3.w);        \
            hv3[0] = (_Float16)d01[0]; hv3[1] = (_Float16)d01[1];             \
            hv3[2] = (_Float16)d23[0]; hv3[3] = (_Float16)d23[1];             \
        }                                                                     \
        *reinterpret_cast<f16x4*>((char*)EH + woff)             = hv0;        \
        *reinterpret_cast<f16x4*>((char*)EH + woff + (1 << 11)) = hv1;        \
        *reinterpret_cast<f16x4*>((char*)EH + woff + (2 << 11)) = hv2;        \
        *reinterpret_cast<f16x4*>((char*)EH + woff + (3 << 11)) = hv3;        \
        _Pragma("unroll")                                                     \
        for (int jj = 0; jj < 4; ++jj) {                                      \
            const int d = sk4 + jj;                                           \
            f16x4 w4;                                                         \
            w4[0] = hv0[jj]; w4[1] = hv1[jj]; w4[2] = hv2[jj]; w4[3] = hv3[jj];\
            *reinterpret_cast<f16x4*>((char*)EHt[(PBUF)] + d * 136 + (srow << 3)) = w4; \
        }                                                                     \
    }

    if (s < sEnd) {   // any non-empty work (uniform across block)
        int c0 = s < sEnd ? st : 0;
        int p  = 0;

        // ---- prologue: stage first chunk into EH + EHt[0] ----
        {
            const int C = min(64, en - c0);
            float4 x0 = (srow      < C) ? *reinterpret_cast<const float4*>(emb + (size_t)(c0 + srow     ) * ND + sk4) : z4;
            float4 x1 = (srow + 16 < C) ? *reinterpret_cast<const float4*>(emb + (size_t)(c0 + srow + 16) * ND + sk4) : z4;
            float4 x2 = (srow + 32 < C) ? *reinterpret_cast<const float4*>(emb + (size_t)(c0 + srow + 32) * ND + sk4) : z4;
            float4 x3 = (srow + 48 < C) ? *reinterpret_cast<const float4*>(emb + (size_t)(c0 + srow + 48) * ND + sk4) : z4;
            CONV_STAGE(x0, x1, x2, x3, C, 0)
        }
        __syncthreads();

        f32x4 acc = {0.f, 0.f, 0.f, 0.f};
        float m = -1e30f, l = 0.f;

        for (;;) {
            const int C = min(64, en - c0);

            // ---- scores for head h; only occupied v-tiles (uniform guard) --
            float sv[4];
            __builtin_amdgcn_s_setprio(1);
#pragma unroll
            for (int vt = 0; vt < 4; ++vt) {
                float sreg = 0.f;
                if ((vt << 4) < C) {
                    const int row = (vt << 4) + vcol;
                    const int rb  = row << 7;
                    const int sw  = (row & 7) << 4;
                    const f16x8 bh0 = *reinterpret_cast<const f16x8*>(
                        (const char*)EH + rb + (((g << 4)) ^ sw));
                    const f16x8 bh1 = *reinterpret_cast<const f16x8*>(
                        (const char*)EH + rb + ((64 | (g << 4)) ^ sw));
#pragma unroll
                    for (int jt = 0; jt < 4; ++jt) {
                        f32x4 a4 = {0.f, 0.f, 0.f, 0.f};
                        a4 = __builtin_amdgcn_mfma_f32_16x16x32_f16(wh[jt][0], bh0, a4, 0, 0, 0);
                        a4 = __builtin_amdgcn_mfma_f32_16x16x32_f16(wh[jt][1], bh1, a4, 0, 0, 0);
                        sreg += a4[0]*a4[0] + a4[1]*a4[1] + a4[2]*a4[2] + a4[3]*a4[3];
                    }
                    sreg += __shfl_xor(sreg, 16, 64);
                    sreg += __shfl_xor(sreg, 32, 64);
                }
                sv[vt] = sreg;
            }
            __builtin_amdgcn_s_setprio(0);

            const float scA = (lane & 16) ? sv[1] : sv[0];
            const float scB = (lane & 16) ? sv[3] : sv[2];
            const float scO = (lane & 32) ? scB : scA;

            // ---- online softmax update (wave-local, head h) ----
            const float sc = (lane < C) ? scO : -1e30f;
            float cmax = sc;
#pragma unroll
            for (int off = 1; off < 64; off <<= 1)
                cmax = fmaxf(cmax, __shfl_xor(cmax, off, 64));
            const float mn = fmaxf(m, cmax);
            const float r  = __expf(m - mn);
            const float e  = (lane < C) ? __expf(sc - mn) : 0.f;
            float csum = e;
#pragma unroll
            for (int off = 1; off < 64; off <<= 1)
                csum += __shfl_xor(csum, off, 64);
            l = l * r + csum;
            m = mn;

            const bool lastOfSample = (c0 + 64 >= en);

            // ---- locate next chunk (empty samples skipped; PFL stays 0) ----
            int ns = s, nc0 = c0 + 64, nen = en;
            if (lastOfSample) {
                ns = s + 1; nc0 = 0; nen = 0;
                while (ns < sEnd) {
                    const int a = start[ns], bb = start[ns + 1];
                    if (a < bb) { nc0 = a; nen = bb; break; }
                    ++ns;
                }
            }
            const bool hasNext = (ns < sEnd) && (nc0 < nen);

            // ---- publish e (f16, k-permuted), r, (l if last) ----
            ELDS[h][epos] = (_Float16)e;
            if (lane == 0) { rbuf[h] = r; if (lastOfSample) lbuf[h] = l; }

            // ---- issue next chunk's global loads (consumed after PV) ----
            float4 x0 = z4, x1 = z4, x2 = z4, x3 = z4;
            int nC = 0;
            if (hasNext) {
                nC = min(64, nen - nc0);
                if (srow      < nC) x0 = *reinterpret_cast<const float4*>(emb + (size_t)(nc0 + srow     ) * ND + sk4);
                if (srow + 16 < nC) x1 = *reinterpret_cast<const float4*>(emb + (size_t)(nc0 + srow + 16) * ND + sk4);
                if (srow + 32 < nC) x2 = *reinterpret_cast<const float4*>(emb + (size_t)(nc0 + srow + 32) * ND + sk4);
                if (srow + 48 < nC) x3 = *reinterpret_cast<const float4*>(emb + (size_t)(nc0 + srow + 48) * ND + sk4);
            }

            __syncthreads();   // barA: e/rbuf/lbuf visible; EH reads done

            // ---- PV: C[m=head][n=d] += e x emb; rescale row m by r_m ----
            {
                const float rb0 = rbuf[0], rb1 = rbuf[1], rb2 = rbuf[2], rb3 = rbuf[3];
                const f16x8 ea0 = *reinterpret_cast<const f16x8*>(&ELDS[vcol][g << 3]);
                const f16x8 ea1 = *reinterpret_cast<const f16x8*>(&ELDS[vcol][(g << 3) + 32]);
                const char* base = (const char*)EHt[p];
                const f16x4 b0lo = *reinterpret_cast<const f16x4*>(base + pvb);
                const f16x4 b0hi = *reinterpret_cast<const f16x4*>(base + pvb + 8);
                const f16x4 b1lo = *reinterpret_cast<const f16x4*>(base + pvb + 64);
                const f16x4 b1hi = *reinterpret_cast<const f16x4*>(base + pvb + 72);
                f16x8 eb0, eb1;
                eb0[0]=b0lo[0]; eb0[1]=b0lo[1]; eb0[2]=b0lo[2]; eb0[3]=b0lo[3];
                eb0[4]=b0hi[0]; eb0[5]=b0hi[1]; eb0[6]=b0hi[2]; eb0[7]=b0hi[3];
                eb1[0]=b1lo[0]; eb1[1]=b1lo[1]; eb1[2]=b1lo[2]; eb1[3]=b1lo[3];
                eb1[4]=b1hi[0]; eb1[5]=b1hi[1]; eb1[6]=b1hi[2]; eb1[7]=b1hi[3];
                acc[0] *= rb0; acc[1] *= rb1; acc[2] *= rb2; acc[3] *= rb3;
                acc = __builtin_amdgcn_mfma_f32_16x16x32_f16(ea0, eb0, acc, 0, 0, 0);
                acc = __builtin_amdgcn_mfma_f32_16x16x32_f16(ea1, eb1, acc, 0, 0, 0);
            }

            // ---- convert + stage next chunk into EH + EHt[p^1] ----
            if (hasNext)
                CONV_STAGE(x0, x1, x2, x3, nC, p ^ 1)

            // ---- sample end: normalized pooled row -> PFL (f16) ----
            if (lastOfSample) {
                if (g == 0) {
                    const int si = s - s0;
#pragma unroll
                    for (int rr = 0; rr < 4; ++rr)
                        PFL[si][rr * 64 + (h << 4) + vcol] =
                            (_Float16)(acc[rr] / lbuf[rr]);
                }
                acc[0] = acc[1] = acc[2] = acc[3] = 0.f;
                m = -1e30f; l = 0.f;
                s = ns; c0 = nc0; en = nen;
            } else {
                c0 = nc0;
            }

            if (!hasNext) break;
            __syncthreads();   // barB: stage visible; PV reads done
            p ^= 1;
        }
    }

    // ---- fused output projection: out[s0+m][:] = PFL[m][:] @ W_out ----
    __syncthreads();   // all PFL writes visible
#pragma unroll
    for (int ntl = 0; ntl < 2; ++ntl) {
        const int nt = (h << 1) + ntl;          // wave's out-col tiles
        f32x4 ao = {0.f, 0.f, 0.f, 0.f};
#pragma unroll
        for (int ks = 0; ks < 8; ++ks) {
            const f16x8 a = *reinterpret_cast<const f16x8*>(
                (const char*)PFL + vcol * 528 + (((ks << 5) + (g << 3)) << 1));
            const f16x8 bq = *reinterpret_cast<const f16x8*>(
                Wfout + ((size_t)((nt << 3) + ks) << 9) + (lane << 3));
            ao = __builtin_amdgcn_mfma_f32_16x16x32_f16(a, bq, ao, 0, 0, 0);
        }
#pragma unroll
        for (int rr = 0; rr < 4; ++rr) {
            const int sm = (g << 2) + rr;       // C row = sample-in-block
            if (sm < GSAMP && s0 + sm < NS)
                out[(size_t)(s0 + sm) * NOUT + (nt << 4) + vcol] = ao[rr];
        }
    }
#undef CONV_STAGE
}

// ---------------------------------------------------------------------------
extern "C" void kernel_launch(void* const* d_in, const int* in_sizes, int n_in,
                              void* d_out, int out_size, void* d_ws, size_t ws_size,
                              hipStream_t stream)
{
    const float* emb  = (const float*)d_in[0];
    const float* Wv   = (const float*)d_in[1];
    const float* Wout = (const float*)d_in[2];
    const int*   map  = (const int*)d_in[3];
    float* out = (float*)d_out;

    char* ws = (char*)d_ws;
    int*      start = (int*)ws;                       //  40,004 B
    _Float16* WfH   = (_Float16*)(ws + 40064);        //  32,768 B
    _Float16* Wfout = (_Float16*)(ws + 72832);        //  65,536 B

    prep_kernel<<<PREP_GRID, 256, 0, stream>>>(Wv, Wout, map, WfH, Wfout, start);
    fused_kernel<<<FUSED_GRID, 256, 0, stream>>>(emb, WfH, Wfout, start, out);
}

// Round 21
// 56.215 us; speedup vs baseline: 1.8389x; 1.0016x over previous
//
#include <hip/hip_runtime.h>

#define NV    500000
#define ND    64
#define NH    4
#define NHID  256
#define NS    10000
#define NOUT  128
#define GSAMP 6                                // samples per block
#define FUSED_GRID ((NS + GSAMP - 1) / GSAMP)  // 1667
#define BOUNDS_BLOCKS ((NV + 255) / 256)       // 1954
#define PREP_GRID (24 + BOUNDS_BLOCKS)

typedef __attribute__((ext_vector_type(8))) _Float16 f16x8;
typedef __attribute__((ext_vector_type(4))) _Float16 f16x4;
typedef __attribute__((ext_vector_type(2))) __fp16   hf16x2;   // cvt_pkrtz result type
typedef __attribute__((ext_vector_type(4))) float    f32x4;

// LDS-only barrier: drain own LDS writes, sync, fence the scheduler.
// Deliberately does NOT drain vmcnt -> global prefetch stays in flight.
__device__ __forceinline__ void bar_lds() {
    asm volatile("s_waitcnt lgkmcnt(0)" ::: "memory");
    __builtin_amdgcn_s_barrier();
    __builtin_amdgcn_sched_barrier(0);
}

// ---------------------------------------------------------------------------
// Prep kernel (single launch): Wv->A-frags | Wout->B-frags | bounds.
// ---------------------------------------------------------------------------
__global__ __launch_bounds__(256) void prep_kernel(
    const float* __restrict__ Wv, const float* __restrict__ Wout,
    const int* __restrict__ map,
    _Float16* __restrict__ WfH, _Float16* __restrict__ Wfout,
    int* __restrict__ start)
{
    const int b = blockIdx.x;
    const int t = threadIdx.x;
    if (b < 8) {
        const int tid  = b * 256 + t;
        const int lane = tid & 63;
        const int slot = tid >> 6;
        const int ks   = slot & 1;
        const int jt   = (slot >> 1) & 3;
        const int h    = slot >> 3;
        const int j    = h * 64 + jt * 16 + (lane & 15);
        const int kb   = ks * 32 + (lane >> 4) * 8;
        f16x8 hv;
#pragma unroll
        for (int i = 0; i < 8; ++i)
            hv[i] = (_Float16)Wv[(size_t)(kb + i) * NHID + j];
        *reinterpret_cast<f16x8*>(WfH + ((size_t)slot << 9) + (lane << 3)) = hv;
    } else if (b < 24) {
        const int tid2 = (b - 8) * 256 + t;
        const int lane = tid2 & 63;
        const int slot = tid2 >> 6;           // nt*8 + ks
        const int ks   = slot & 7;
        const int nt   = slot >> 3;
        const int n    = (nt << 4) + (lane & 15);
        const int kb   = (ks << 5) + ((lane >> 4) << 3);
        f16x8 hv;
#pragma unroll
        for (int i = 0; i < 8; ++i)
            hv[i] = (_Float16)Wout[(size_t)(kb + i) * NOUT + n];
        *reinterpret_cast<f16x8*>(Wfout + ((size_t)slot << 9) + (lane << 3)) = hv;
    } else {
        const int v = (b - 24) * 256 + t;
        if (v >= NV) return;
        const int cur = map[v];
        if (v == 0) {
            for (int s = 0; s <= cur; ++s) start[s] = 0;
        } else {
            const int prev = map[v - 1];
            for (int s = prev + 1; s <= cur; ++s) start[s] = v;
        }
        if (v == NV - 1) {
            for (int s = cur + 1; s <= NS; ++s) start[s] = NV;
        }
    }
}

// ---------------------------------------------------------------------------
// Fused (R21): R20 structure with (a) LDS-only barA/barB so the global
// prefetch survives the barrier, (b) next-chunk load issue hoisted to the
// top of each chunk -> overlap = scores+softmax+barA+PV. Numerics = R20.
// ---------------------------------------------------------------------------
__global__ __launch_bounds__(256, 4) void fused_kernel(
    const float* __restrict__ emb,
    const _Float16* __restrict__ WfH, const _Float16* __restrict__ Wfout,
    const int* __restrict__ start, float* __restrict__ out)
{
    __shared__ _Float16 EH[64 * 64];      // emb hi, row-major swizzled (8 KB)
    __shared__ _Float16 EHt[2][64 * 68];  // emb hi, d-major, v'-permuted (2x8.5 KB)
    __shared__ _Float16 ELDS[16][72];     // e-matrix, k-permuted, padded (2.25 KB)
    __shared__ _Float16 PFL[16][264];     // pooled rows (f16), padded (8.25 KB)
    __shared__ float    rbuf[NH];
    __shared__ float    lbuf[NH];

    const int t    = threadIdx.x;
    const int lane = t & 63;
    const int h    = t >> 6;
    const int vcol = lane & 15;
    const int g    = lane >> 4;

    f16x8 wh[4][2];
#pragma unroll
    for (int jt = 0; jt < 4; ++jt)
#pragma unroll
        for (int ks = 0; ks < 2; ++ks) {
            const int slot = ((h * 4 + jt) * 2 + ks);
            wh[jt][ks] = *reinterpret_cast<const f16x8*>(
                WfH + ((size_t)slot << 9) + (lane << 3));
        }

    for (int i = t; i < (16 * 72 * 2) / 4; i += 256)
        reinterpret_cast<unsigned*>(ELDS)[i] = 0u;
    for (int i = t; i < (16 * 264 * 2) / 4; i += 256)
        reinterpret_cast<unsigned*>(PFL)[i] = 0u;
    __syncthreads();

    const int s0   = blockIdx.x * GSAMP;
    const int sEnd = (s0 + GSAMP < NS) ? (s0 + GSAMP) : NS;
    const int srow = t >> 4;
    const int sk4  = (t & 15) << 2;
    const int woff = (srow << 7) + ((sk4 << 1) ^ ((srow & 7) << 4));

    const int dpv  = (h << 4) + vcol;
    const int pvb  = dpv * 136 + (g << 4);
    const int epos = ((lane & 15) << 2) + (lane >> 4);

    int s = s0, st = 0, en = 0;
    while (s < sEnd) {
        st = start[s]; en = start[s + 1];
        if (st < en) break;
        ++s;
    }

    const float4 z4 = make_float4(0.f, 0.f, 0.f, 0.f);

#define CONV_STAGE(X0, X1, X2, X3, CC, PBUF)                                  \
    {                                                                         \
        const float4 y0 = (srow      < (CC)) ? (X0) : z4;                     \
        const float4 y1 = (srow + 16 < (CC)) ? (X1) : z4;                     \
        const float4 y2 = (srow + 32 < (CC)) ? (X2) : z4;                     \
        const float4 y3 = (srow + 48 < (CC)) ? (X3) : z4;                     \
        f16x4 hv0, hv1, hv2, hv3;                                             \
        {                                                                     \
            const hf16x2 a01 = __builtin_amdgcn_cvt_pkrtz(y0.x, y0.y);        \
            const hf16x2 a23 = __builtin_amdgcn_cvt_pkrtz(y0.z, y0.w);        \
            hv0[0] = (_Float16)a01[0]; hv0[1] = (_Float16)a01[1];             \
            hv0[2] = (_Float16)a23[0]; hv0[3] = (_Float16)a23[1];             \
            const hf16x2 b01 = __builtin_amdgcn_cvt_pkrtz(y1.x, y1.y);        \
            const hf16x2 b23 = __builtin_amdgcn_cvt_pkrtz(y1.z, y1.w);        \
            hv1[0] = (_Float16)b01[0]; hv1[1] = (_Float16)b01[1];             \
            hv1[2] = (_Float16)b23[0]; hv1[3] = (_Float16)b23[1];             \
            const hf16x2 c01 = __builtin_amdgcn_cvt_pkrtz(y2.x, y2.y);        \
            const hf16x2 c23 = __builtin_amdgcn_cvt_pkrtz(y2.z, y2.w);        \
            hv2[0] = (_Float16)c01[0]; hv2[1] = (_Float16)c01[1];             \
            hv2[2] = (_Float16)c23[0]; hv2[3] = (_Float16)c23[1];             \
            const hf16x2 d01 = __builtin_amdgcn_cvt_pkrtz(y3.x, y3.y);        \
            const hf16x2 d23 = __builtin_amdgcn_cvt_pkrtz(y3.z, y3.w);        \
            hv3[0] = (_Float16)d01[0]; hv3[1] = (_Float16)d01[1];             \
            hv3[2] = (_Float16)d23[0]; hv3[3] = (_Float16)d23[1];             \
        }                                                                     \
        *reinterpret_cast<f16x4*>((char*)EH + woff)             = hv0;        \
        *reinterpret_cast<f16x4*>((char*)EH + woff + (1 << 11)) = hv1;        \
        *reinterpret_cast<f16x4*>((char*)EH + woff + (2 << 11)) = hv2;        \
        *reinterpret_cast<f16x4*>((char*)EH + woff + (3 << 11)) = hv3;        \
        _Pragma("unroll")                                                     \
        for (int jj = 0; jj < 4; ++jj) {                                      \
            const int d = sk4 + jj;                                           \
            f16x4 w4;                                                         \
            w4[0] = hv0[jj]; w4[1] = hv1[jj]; w4[2] = hv2[jj]; w4[3] = hv3[jj];\
            *reinterpret_cast<f16x4*>((char*)EHt[(PBUF)] + d * 136 + (srow << 3)) = w4; \
        }                                                                     \
    }

    if (s < sEnd) {
        int c0 = st;
        int p  = 0;

        // ---- prologue: stage first chunk ----
        {
            const int C = min(64, en - c0);
            float4 x0 = (srow      < C) ? *reinterpret_cast<const float4*>(emb + (size_t)(c0 + srow     ) * ND + sk4) : z4;
            float4 x1 = (srow + 16 < C) ? *reinterpret_cast<const float4*>(emb + (size_t)(c0 + srow + 16) * ND + sk4) : z4;
            float4 x2 = (srow + 32 < C) ? *reinterpret_cast<const float4*>(emb + (size_t)(c0 + srow + 32) * ND + sk4) : z4;
            float4 x3 = (srow + 48 < C) ? *reinterpret_cast<const float4*>(emb + (size_t)(c0 + srow + 48) * ND + sk4) : z4;
            CONV_STAGE(x0, x1, x2, x3, C, 0)
        }
        __syncthreads();

        f32x4 acc = {0.f, 0.f, 0.f, 0.f};
        float m = -1e30f, l = 0.f;

        for (;;) {
            const int C = min(64, en - c0);
            const bool lastOfSample = (c0 + 64 >= en);

            // ---- locate next chunk + ISSUE its loads now (chunk top) ----
            int ns = s, nc0 = c0 + 64, nen = en;
            if (lastOfSample) {
                ns = s + 1; nc0 = 0; nen = 0;
                while (ns < sEnd) {
                    const int a = start[ns], bb = start[ns + 1];
                    if (a < bb) { nc0 = a; nen = bb; break; }
                    ++ns;
                }
            }
            const bool hasNext = (ns < sEnd) && (nc0 < nen);
            float4 x0 = z4, x1 = z4, x2 = z4, x3 = z4;
            int nC = 0;
            if (hasNext) {
                nC = min(64, nen - nc0);
                if (srow      < nC) x0 = *reinterpret_cast<const float4*>(emb + (size_t)(nc0 + srow     ) * ND + sk4);
                if (srow + 16 < nC) x1 = *reinterpret_cast<const float4*>(emb + (size_t)(nc0 + srow + 16) * ND + sk4);
                if (srow + 32 < nC) x2 = *reinterpret_cast<const float4*>(emb + (size_t)(nc0 + srow + 32) * ND + sk4);
                if (srow + 48 < nC) x3 = *reinterpret_cast<const float4*>(emb + (size_t)(nc0 + srow + 48) * ND + sk4);
            }

            // ---- scores for head h; only occupied v-tiles ----
            float sv[4];
            __builtin_amdgcn_s_setprio(1);
#pragma unroll
            for (int vt = 0; vt < 4; ++vt) {
                float sreg = 0.f;
                if ((vt << 4) < C) {
                    const int row = (vt << 4) + vcol;
                    const int rb  = row << 7;
                    const int sw  = (row & 7) << 4;
                    const f16x8 bh0 = *reinterpret_cast<const f16x8*>(
                        (const char*)EH + rb + (((g << 4)) ^ sw));
                    const f16x8 bh1 = *reinterpret_cast<const f16x8*>(
                        (const char*)EH + rb + ((64 | (g << 4)) ^ sw));
#pragma unroll
                    for (int jt = 0; jt < 4; ++jt) {
                        f32x4 a4 = {0.f, 0.f, 0.f, 0.f};
                        a4 = __builtin_amdgcn_mfma_f32_16x16x32_f16(wh[jt][0], bh0, a4, 0, 0, 0);
                        a4 = __builtin_amdgcn_mfma_f32_16x16x32_f16(wh[jt][1], bh1, a4, 0, 0, 0);
                        sreg += a4[0]*a4[0] + a4[1]*a4[1] + a4[2]*a4[2] + a4[3]*a4[3];
                    }
                    sreg += __shfl_xor(sreg, 16, 64);
                    sreg += __shfl_xor(sreg, 32, 64);
                }
                sv[vt] = sreg;
            }
            __builtin_amdgcn_s_setprio(0);

            const float scA = (lane & 16) ? sv[1] : sv[0];
            const float scB = (lane & 16) ? sv[3] : sv[2];
            const float scO = (lane & 32) ? scB : scA;

            // ---- online softmax update ----
            const float sc = (lane < C) ? scO : -1e30f;
            float cmax = sc;
#pragma unroll
            for (int off = 1; off < 64; off <<= 1)
                cmax = fmaxf(cmax, __shfl_xor(cmax, off, 64));
            const float mn = fmaxf(m, cmax);
            const float r  = __expf(m - mn);
            const float e  = (lane < C) ? __expf(sc - mn) : 0.f;
            float csum = e;
#pragma unroll
            for (int off = 1; off < 64; off <<= 1)
                csum += __shfl_xor(csum, off, 64);
            l = l * r + csum;
            m = mn;

            // ---- publish e, r, (l if last) ----
            ELDS[h][epos] = (_Float16)e;
            if (lane == 0) { rbuf[h] = r; if (lastOfSample) lbuf[h] = l; }

            bar_lds();   // barA: LDS-only -> prefetch stays in flight

            // ---- PV ----
            {
                const float rb0 = rbuf[0], rb1 = rbuf[1], rb2 = rbuf[2], rb3 = rbuf[3];
                const f16x8 ea0 = *reinterpret_cast<const f16x8*>(&ELDS[vcol][g << 3]);
                const f16x8 ea1 = *reinterpret_cast<const f16x8*>(&ELDS[vcol][(g << 3) + 32]);
                const char* base = (const char*)EHt[p];
                const f16x4 b0lo = *reinterpret_cast<const f16x4*>(base + pvb);
                const f16x4 b0hi = *reinterpret_cast<const f16x4*>(base + pvb + 8);
                const f16x4 b1lo = *reinterpret_cast<const f16x4*>(base + pvb + 64);
                const f16x4 b1hi = *reinterpret_cast<const f16x4*>(base + pvb + 72);
                f16x8 eb0, eb1;
                eb0[0]=b0lo[0]; eb0[1]=b0lo[1]; eb0[2]=b0lo[2]; eb0[3]=b0lo[3];
                eb0[4]=b0hi[0]; eb0[5]=b0hi[1]; eb0[6]=b0hi[2]; eb0[7]=b0hi[3];
                eb1[0]=b1lo[0]; eb1[1]=b1lo[1]; eb1[2]=b1lo[2]; eb1[3]=b1lo[3];
                eb1[4]=b1hi[0]; eb1[5]=b1hi[1]; eb1[6]=b1hi[2]; eb1[7]=b1hi[3];
                acc[0] *= rb0; acc[1] *= rb1; acc[2] *= rb2; acc[3] *= rb3;
                acc = __builtin_amdgcn_mfma_f32_16x16x32_f16(ea0, eb0, acc, 0, 0, 0);
                acc = __builtin_amdgcn_mfma_f32_16x16x32_f16(ea1, eb1, acc, 0, 0, 0);
            }

            // ---- convert + stage next chunk (vmcnt drains here) ----
            if (hasNext)
                CONV_STAGE(x0, x1, x2, x3, nC, p ^ 1)

            // ---- sample end: normalized pooled row -> PFL (f16) ----
            if (lastOfSample) {
                if (g == 0) {
                    const int si = s - s0;
#pragma unroll
                    for (int rr = 0; rr < 4; ++rr)
                        PFL[si][rr * 64 + (h << 4) + vcol] =
                            (_Float16)(acc[rr] / lbuf[rr]);
                }
                acc[0] = acc[1] = acc[2] = acc[3] = 0.f;
                m = -1e30f; l = 0.f;
                s = ns; c0 = nc0; en = nen;
            } else {
                c0 = nc0;
            }

            if (!hasNext) break;
            bar_lds();   // barB: LDS-only
            p ^= 1;
        }
    }

    // ---- fused output projection: out[s0+m][:] = PFL[m][:] @ W_out ----
    __syncthreads();
#pragma unroll
    for (int ntl = 0; ntl < 2; ++ntl) {
        const int nt = (h << 1) + ntl;
        f32x4 ao = {0.f, 0.f, 0.f, 0.f};
#pragma unroll
        for (int ks = 0; ks < 8; ++ks) {
            const f16x8 a = *reinterpret_cast<const f16x8*>(
                (const char*)PFL + vcol * 528 + (((ks << 5) + (g << 3)) << 1));
            const f16x8 bq = *reinterpret_cast<const f16x8*>(
                Wfout + ((size_t)((nt << 3) + ks) << 9) + (lane << 3));
            ao = __builtin_amdgcn_mfma_f32_16x16x32_f16(a, bq, ao, 0, 0, 0);
        }
#pragma unroll
        for (int rr = 0; rr < 4; ++rr) {
            const int sm = (g << 2) + rr;
            if (sm < GSAMP && s0 + sm < NS)
                out[(size_t)(s0 + sm) * NOUT + (nt << 4) + vcol] = ao[rr];
        }
    }
#undef CONV_STAGE
}

// ---------------------------------------------------------------------------
extern "C" void kernel_launch(void* const* d_in, const int* in_sizes, int n_in,
                              void* d_out, int out_size, void* d_ws, size_t ws_size,
                              hipStream_t stream)
{
    const float* emb  = (const float*)d_in[0];
    const float* Wv   = (const float*)d_in[1];
    const float* Wout = (const float*)d_in[2];
    const int*   map  = (const int*)d_in[3];
    float* out = (float*)d_out;

    char* ws = (char*)d_ws;
    int*      start = (int*)ws;                       //  40,004 B
    _Float16* WfH   = (_Float16*)(ws + 40064);        //  32,768 B
    _Float16* Wfout = (_Float16*)(ws + 72832);        //  65,536 B

    prep_kernel<<<PREP_GRID, 256, 0, stream>>>(Wv, Wout, map, WfH, Wfout, start);
    fused_kernel<<<FUSED_GRID, 256, 0, stream>>>(emb, WfH, Wfout, start, out);
}